// Round 1
// baseline (2964.708 us; speedup 1.0000x reference)
//
#include <hip/hip_runtime.h>
#include <stdint.h>

#define N_NODES 50000
#define N_EDGES 800000
#define D 128
#define DOUT 64

__host__ __device__ inline uint32_t rotl32(uint32_t v, int d) {
    return (v << d) | (v >> (32 - d));
}

// JAX threefry2x32 (20 rounds), matches jax/_src/prng.py
__host__ __device__ inline void threefry2x32(uint32_t k0, uint32_t k1,
                                             uint32_t x0, uint32_t x1,
                                             uint32_t& o0, uint32_t& o1) {
    uint32_t ks2 = 0x1BD11BDAu ^ k0 ^ k1;
    x0 += k0; x1 += k1;
#define TFR(d) { x0 += x1; x1 = rotl32(x1, d); x1 ^= x0; }
    TFR(13) TFR(15) TFR(26) TFR(6)
    x0 += k1;  x1 += ks2 + 1u;
    TFR(17) TFR(29) TFR(16) TFR(24)
    x0 += ks2; x1 += k0 + 2u;
    TFR(13) TFR(15) TFR(26) TFR(6)
    x0 += k0;  x1 += k1 + 3u;
    TFR(17) TFR(29) TFR(16) TFR(24)
    x0 += k1;  x1 += ks2 + 4u;
    TFR(13) TFR(15) TFR(26) TFR(6)
    x0 += ks2; x1 += k0 + 5u;
#undef TFR
    o0 = x0; o1 = x1;
}

// partitionable random_bits(32) for flat index j: bits = x0^x1 of threefry(key,(0,j))
__device__ inline bool keep_mask(uint32_t k0, uint32_t k1, uint32_t j) {
    uint32_t b0, b1;
    threefry2x32(k0, k1, 0u, j, b0, b1);
    uint32_t bits = b0 ^ b1;
    float u = __uint_as_float((bits >> 9) | 0x3f800000u) - 1.0f;
    return u < 0.5f;
}

__global__ void drop_kernel(const float* __restrict__ x, float* __restrict__ y,
                            uint32_t k0, uint32_t k1, int n) {
    int j = blockIdx.x * blockDim.x + threadIdx.x;
    if (j < n) {
        float v = x[j];
        y[j] = keep_mask(k0, k1, (uint32_t)j) ? v * 2.0f : 0.0f;
    }
}

// 32 lanes per edge; float4 per lane covers D=128
__global__ __launch_bounds__(256) void spmm_kernel(const int* __restrict__ rows,
                                                   const int* __restrict__ cols,
                                                   const float* __restrict__ w,
                                                   const float* __restrict__ h,
                                                   float* __restrict__ out) {
    int t = blockIdx.x * blockDim.x + threadIdx.x;
    int e = t >> 5;
    if (e >= N_EDGES) return;
    int lane = t & 31;
    int r = rows[e];
    int c = cols[e];
    float we = w[e];
    float4 v = ((const float4*)(h + (size_t)c * D))[lane];
    float* op = out + (size_t)r * D + lane * 4;
    atomicAdd(op + 0, we * v.x);
    atomicAdd(op + 1, we * v.y);
    atomicAdd(op + 2, we * v.z);
    atomicAdd(op + 3, we * v.w);
}

// out = dropout(relu(s @ W1 + b1)); W1 staged in LDS (64KB)
#define L1_ROWS 32
__global__ __launch_bounds__(256) void lin1_kernel(const float* __restrict__ s,
                                                   const float* __restrict__ W1,
                                                   const float* __restrict__ b1,
                                                   float* __restrict__ out,
                                                   uint32_t k0, uint32_t k1) {
    __shared__ float w[128 * 128];
    for (int i = threadIdx.x; i < 128 * 128 / 4; i += 256)
        ((float4*)w)[i] = ((const float4*)W1)[i];
    __syncthreads();

    int rowBase = blockIdx.x * L1_ROWS;
    int c = threadIdx.x & 127;
    int rsub = threadIdx.x >> 7;  // 0..1
    float bias = b1[c];
    for (int rr = rsub; rr < L1_ROWS; rr += 2) {
        int row = rowBase + rr;
        if (row >= N_NODES) break;
        const float* srow = s + (size_t)row * 128;
        float acc = 0.f;
#pragma unroll 8
        for (int k = 0; k < 128; ++k) acc += srow[k] * w[k * 128 + c];
        acc += bias;
        acc = fmaxf(acc, 0.f);
        uint32_t j = (uint32_t)row * 128u + (uint32_t)c;
        out[(size_t)row * 128 + c] = keep_mask(k0, k1, j) ? acc * 2.f : 0.f;
    }
}

// out = s @ W2 + b2; W2 staged in LDS (32KB)
#define L2_ROWS 32
__global__ __launch_bounds__(256) void lin2_kernel(const float* __restrict__ s,
                                                   const float* __restrict__ W2,
                                                   const float* __restrict__ b2,
                                                   float* __restrict__ out) {
    __shared__ float w[128 * 64];
    for (int i = threadIdx.x; i < 128 * 64 / 4; i += 256)
        ((float4*)w)[i] = ((const float4*)W2)[i];
    __syncthreads();

    int rowBase = blockIdx.x * L2_ROWS;
    int c = threadIdx.x & 63;
    int rsub = threadIdx.x >> 6;  // 0..3
    float bias = b2[c];
    for (int rr = rsub; rr < L2_ROWS; rr += 4) {
        int row = rowBase + rr;
        if (row >= N_NODES) break;
        const float* srow = s + (size_t)row * 128;
        float acc = 0.f;
#pragma unroll 8
        for (int k = 0; k < 128; ++k) acc += srow[k] * w[k * 64 + c];
        out[(size_t)row * 64 + c] = acc + bias;
    }
}

extern "C" void kernel_launch(void* const* d_in, const int* in_sizes, int n_in,
                              void* d_out, int out_size, void* d_ws, size_t ws_size,
                              hipStream_t stream) {
    const int*   rows = (const int*)d_in[0];
    const int*   cols = (const int*)d_in[1];
    const float* w    = (const float*)d_in[2];
    const float* X    = (const float*)d_in[3];
    const float* W1   = (const float*)d_in[4];
    const float* b1   = (const float*)d_in[5];
    const float* W2   = (const float*)d_in[6];
    const float* b2   = (const float*)d_in[7];
    float* out = (float*)d_out;

    size_t matBytes = (size_t)N_NODES * D * sizeof(float);
    float* A = (float*)d_ws;                          // h buffer (dropout out / lin1 out)
    float* B = (float*)((char*)d_ws + matBytes);      // SpMM accumulator

    // Host-side key derivation: split(key(42)) under threefry-partitionable
    uint32_t ka0, ka1, kb0, kb1;
    threefry2x32(0u, 42u, 0u, 0u, ka0, ka1);  // k1 (drop1)
    threefry2x32(0u, 42u, 0u, 1u, kb0, kb1);  // k2 (drop2)

    int nElem = N_NODES * D;

    hipMemsetAsync(B, 0, matBytes, stream);
    drop_kernel<<<(nElem + 255) / 256, 256, 0, stream>>>(X, A, ka0, ka1, nElem);
    spmm_kernel<<<((size_t)N_EDGES * 32 + 255) / 256, 256, 0, stream>>>(rows, cols, w, A, B);
    lin1_kernel<<<(N_NODES + L1_ROWS - 1) / L1_ROWS, 256, 0, stream>>>(B, W1, b1, A, kb0, kb1);
    hipMemsetAsync(B, 0, matBytes, stream);
    spmm_kernel<<<((size_t)N_EDGES * 32 + 255) / 256, 256, 0, stream>>>(rows, cols, w, A, B);
    lin2_kernel<<<(N_NODES + L2_ROWS - 1) / L2_ROWS, 256, 0, stream>>>(B, W2, b2, out);
}

// Round 5
// 603.268 us; speedup vs baseline: 4.9144x; 4.9144x over previous
//
#include <hip/hip_runtime.h>
#include <stdint.h>

#define N_NODES 50000
#define N_EDGES 800000
#define D 128
#define DOUT 64

__host__ __device__ inline uint32_t rotl32(uint32_t v, int d) {
    return (v << d) | (v >> (32 - d));
}

// JAX threefry2x32 (20 rounds), matches jax/_src/prng.py
__host__ __device__ inline void threefry2x32(uint32_t k0, uint32_t k1,
                                             uint32_t x0, uint32_t x1,
                                             uint32_t& o0, uint32_t& o1) {
    uint32_t ks2 = 0x1BD11BDAu ^ k0 ^ k1;
    x0 += k0; x1 += k1;
#define TFR(d) { x0 += x1; x1 = rotl32(x1, d); x1 ^= x0; }
    TFR(13) TFR(15) TFR(26) TFR(6)
    x0 += k1;  x1 += ks2 + 1u;
    TFR(17) TFR(29) TFR(16) TFR(24)
    x0 += ks2; x1 += k0 + 2u;
    TFR(13) TFR(15) TFR(26) TFR(6)
    x0 += k0;  x1 += k1 + 3u;
    TFR(17) TFR(29) TFR(16) TFR(24)
    x0 += k1;  x1 += ks2 + 4u;
    TFR(13) TFR(15) TFR(26) TFR(6)
    x0 += ks2; x1 += k0 + 5u;
#undef TFR
    o0 = x0; o1 = x1;
}

// partitionable random_bits(32) for flat index j: bits = x0^x1 of threefry(key,(0,j))
__device__ inline bool keep_mask(uint32_t k0, uint32_t k1, uint32_t j) {
    uint32_t b0, b1;
    threefry2x32(k0, k1, 0u, j, b0, b1);
    uint32_t bits = b0 ^ b1;
    float u = __uint_as_float((bits >> 9) | 0x3f800000u) - 1.0f;
    return u < 0.5f;
}

__global__ void drop_kernel(const float* __restrict__ x, float* __restrict__ y,
                            uint32_t k0, uint32_t k1, int n) {
    int j = blockIdx.x * blockDim.x + threadIdx.x;
    if (j < n) {
        float v = x[j];
        y[j] = keep_mask(k0, k1, (uint32_t)j) ? v * 2.0f : 0.0f;
    }
}

// ---------------- CSR build ----------------

__global__ void hist_kernel(const int* __restrict__ rows, int* __restrict__ deg) {
    int e = blockIdx.x * blockDim.x + threadIdx.x;
    if (e < N_EDGES) {
        int r = rows[e];
        if (r >= 0 && r < N_NODES) atomicAdd(&deg[r], 1);
    }
}

#define SCAN_T 1024
// single-block exclusive scan of deg[N_NODES] -> start[N_NODES+1], cursor[N_NODES]
// alias-safe: deg[idx] read into a temp before any write
__global__ __launch_bounds__(SCAN_T) void scan_kernel(const int* __restrict__ deg,
                                                      int* __restrict__ start,
                                                      int* __restrict__ cursor) {
    __shared__ int sums[SCAN_T];
    int tid = threadIdx.x;
    const int per = (N_NODES + SCAN_T - 1) / SCAN_T;  // 49
    int base = tid * per;
    int s = 0;
    for (int i = 0; i < per; ++i) {
        int idx = base + i;
        if (idx < N_NODES) s += deg[idx];
    }
    sums[tid] = s;
    __syncthreads();
    // Hillis-Steele inclusive scan
    for (int off = 1; off < SCAN_T; off <<= 1) {
        int v = (tid >= off) ? sums[tid - off] : 0;
        __syncthreads();
        if (tid >= off) sums[tid] += v;
        __syncthreads();
    }
    int run = (tid == 0) ? 0 : sums[tid - 1];
    for (int i = 0; i < per; ++i) {
        int idx = base + i;
        if (idx < N_NODES) {
            int d = deg[idx];          // read BEFORE writes (alias-safe)
            start[idx] = run;
            cursor[idx] = run;
            run += d;
        }
    }
    if (tid == SCAN_T - 1) start[N_NODES] = sums[SCAN_T - 1];
}

__global__ void scatter_kernel(const int* __restrict__ rows, const int* __restrict__ cols,
                               const float* __restrict__ w, int* __restrict__ cursor,
                               int* __restrict__ ecol, float* __restrict__ ew) {
    int e = blockIdx.x * blockDim.x + threadIdx.x;
    if (e < N_EDGES) {
        int r = rows[e];
        if (r < 0 || r >= N_NODES) return;            // defensive
        int pos = atomicAdd(&cursor[r], 1);
        if (pos < 0 || pos >= N_EDGES) return;        // defensive: never write OOB
        ecol[pos] = cols[e];
        ew[pos] = w[e];
    }
}

// ---------------- SpMM (CSR, gather, no output atomics) ----------------
// 32 lanes per row, float4 per lane covers D=128
__global__ __launch_bounds__(256) void spmm_csr(const int* __restrict__ start,
                                                const int* __restrict__ ecol,
                                                const float* __restrict__ ew,
                                                const float* __restrict__ h,
                                                float* __restrict__ out) {
    int t = blockIdx.x * blockDim.x + threadIdx.x;
    int r = t >> 5;
    if (r >= N_NODES) return;
    int lane = t & 31;
    int s0 = start[r], s1 = start[r + 1];
    float4 acc = make_float4(0.f, 0.f, 0.f, 0.f);
    for (int i = s0; i < s1; ++i) {
        int c = ecol[i];
        float we = ew[i];
        float4 v = ((const float4*)(h + (size_t)c * D))[lane];
        acc.x += we * v.x;
        acc.y += we * v.y;
        acc.z += we * v.z;
        acc.w += we * v.w;
    }
    ((float4*)(out + (size_t)r * D))[lane] = acc;
}

// ---------------- fallback SpMM (atomics) ----------------
__global__ __launch_bounds__(256) void spmm_kernel(const int* __restrict__ rows,
                                                   const int* __restrict__ cols,
                                                   const float* __restrict__ w,
                                                   const float* __restrict__ h,
                                                   float* __restrict__ out) {
    int t = blockIdx.x * blockDim.x + threadIdx.x;
    int e = t >> 5;
    if (e >= N_EDGES) return;
    int lane = t & 31;
    int r = rows[e];
    int c = cols[e];
    float we = w[e];
    float4 v = ((const float4*)(h + (size_t)c * D))[lane];
    float* op = out + (size_t)r * D + lane * 4;
    atomicAdd(op + 0, we * v.x);
    atomicAdd(op + 1, we * v.y);
    atomicAdd(op + 2, we * v.z);
    atomicAdd(op + 3, we * v.w);
}

// out = dropout(relu(s @ W1 + b1)); W1 staged in LDS (64KB)
#define L1_ROWS 32
__global__ __launch_bounds__(256) void lin1_kernel(const float* __restrict__ s,
                                                   const float* __restrict__ W1,
                                                   const float* __restrict__ b1,
                                                   float* __restrict__ out,
                                                   uint32_t k0, uint32_t k1) {
    __shared__ float w[128 * 128];
    for (int i = threadIdx.x; i < 128 * 128 / 4; i += 256)
        ((float4*)w)[i] = ((const float4*)W1)[i];
    __syncthreads();

    int rowBase = blockIdx.x * L1_ROWS;
    int c = threadIdx.x & 127;
    int rsub = threadIdx.x >> 7;  // 0..1
    float bias = b1[c];
    for (int rr = rsub; rr < L1_ROWS; rr += 2) {
        int row = rowBase + rr;
        if (row >= N_NODES) break;
        const float* srow = s + (size_t)row * 128;
        float acc = 0.f;
#pragma unroll 8
        for (int k = 0; k < 128; ++k) acc += srow[k] * w[k * 128 + c];
        acc += bias;
        acc = fmaxf(acc, 0.f);
        uint32_t j = (uint32_t)row * 128u + (uint32_t)c;
        out[(size_t)row * 128 + c] = keep_mask(k0, k1, j) ? acc * 2.f : 0.f;
    }
}

// out = s @ W2 + b2; W2 staged in LDS (32KB)
#define L2_ROWS 32
__global__ __launch_bounds__(256) void lin2_kernel(const float* __restrict__ s,
                                                   const float* __restrict__ W2,
                                                   const float* __restrict__ b2,
                                                   float* __restrict__ out) {
    __shared__ float w[128 * 64];
    for (int i = threadIdx.x; i < 128 * 64 / 4; i += 256)
        ((float4*)w)[i] = ((const float4*)W2)[i];
    __syncthreads();

    int rowBase = blockIdx.x * L2_ROWS;
    int c = threadIdx.x & 63;
    int rsub = threadIdx.x >> 6;  // 0..3
    float bias = b2[c];
    for (int rr = rsub; rr < L2_ROWS; rr += 4) {
        int row = rowBase + rr;
        if (row >= N_NODES) break;
        const float* srow = s + (size_t)row * 128;
        float acc = 0.f;
#pragma unroll 8
        for (int k = 0; k < 128; ++k) acc += srow[k] * w[k * 64 + c];
        out[(size_t)row * 64 + c] = acc + bias;
    }
}

extern "C" void kernel_launch(void* const* d_in, const int* in_sizes, int n_in,
                              void* d_out, int out_size, void* d_ws, size_t ws_size,
                              hipStream_t stream) {
    const int*   rows = (const int*)d_in[0];
    const int*   cols = (const int*)d_in[1];
    const float* w    = (const float*)d_in[2];
    const float* X    = (const float*)d_in[3];
    const float* W1   = (const float*)d_in[4];
    const float* b1   = (const float*)d_in[5];
    const float* W2   = (const float*)d_in[6];
    const float* b2   = (const float*)d_in[7];
    float* out = (float*)d_out;

    size_t matBytes = (size_t)N_NODES * D * sizeof(float);  // 25.6 MB

    // Host-side key derivation: split(key(42)) under threefry-partitionable
    uint32_t ka0, ka1, kb0, kb1;
    threefry2x32(0u, 42u, 0u, 0u, ka0, ka1);  // k1 (drop1)
    threefry2x32(0u, 42u, 0u, 1u, kb0, kb1);  // k2 (drop2)

    int nElem = N_NODES * D;

    // workspace layout (all buffers distinct — NO aliasing)
    char* p = (char*)d_ws;
    float* A      = (float*)p;                 p += matBytes;
    float* B      = (float*)p;                 p += matBytes;
    int*   ecol   = (int*)p;                   p += (size_t)N_EDGES * 4;
    float* ew     = (float*)p;                 p += (size_t)N_EDGES * 4;
    int*   start  = (int*)p;                   p += (size_t)(N_NODES + 1) * 4;
    int*   cursor = (int*)p;                   p += (size_t)N_NODES * 4;
    int*   deg    = (int*)p;                   p += (size_t)N_NODES * 4;
    size_t needed = (size_t)(p - (char*)d_ws);

    if (ws_size >= needed) {
        // ---- CSR path ----
        hipMemsetAsync(deg, 0, (size_t)N_NODES * 4, stream);
        hist_kernel<<<(N_EDGES + 255) / 256, 256, 0, stream>>>(rows, deg);
        scan_kernel<<<1, SCAN_T, 0, stream>>>(deg, start, cursor);
        scatter_kernel<<<(N_EDGES + 255) / 256, 256, 0, stream>>>(rows, cols, w, cursor, ecol, ew);

        drop_kernel<<<(nElem + 255) / 256, 256, 0, stream>>>(X, A, ka0, ka1, nElem);
        spmm_csr<<<((size_t)N_NODES * 32 + 255) / 256, 256, 0, stream>>>(start, ecol, ew, A, B);
        lin1_kernel<<<(N_NODES + L1_ROWS - 1) / L1_ROWS, 256, 0, stream>>>(B, W1, b1, A, kb0, kb1);
        spmm_csr<<<((size_t)N_NODES * 32 + 255) / 256, 256, 0, stream>>>(start, ecol, ew, A, B);
        lin2_kernel<<<(N_NODES + L2_ROWS - 1) / L2_ROWS, 256, 0, stream>>>(B, W2, b2, out);
    } else {
        // ---- fallback: atomic path (round-1, known-good) ----
        float* FA = (float*)d_ws;
        float* FB = (float*)((char*)d_ws + matBytes);
        hipMemsetAsync(FB, 0, matBytes, stream);
        drop_kernel<<<(nElem + 255) / 256, 256, 0, stream>>>(X, FA, ka0, ka1, nElem);
        spmm_kernel<<<((size_t)N_EDGES * 32 + 255) / 256, 256, 0, stream>>>(rows, cols, w, FA, FB);
        lin1_kernel<<<(N_NODES + L1_ROWS - 1) / L1_ROWS, 256, 0, stream>>>(FB, W1, b1, FA, kb0, kb1);
        hipMemsetAsync(FB, 0, matBytes, stream);
        spmm_kernel<<<((size_t)N_EDGES * 32 + 255) / 256, 256, 0, stream>>>(rows, cols, w, FA, FB);
        lin2_kernel<<<(N_NODES + L2_ROWS - 1) / L2_ROWS, 256, 0, stream>>>(FB, W2, b2, out);
    }
}

// Round 6
// 428.365 us; speedup vs baseline: 6.9210x; 1.4083x over previous
//
#include <hip/hip_runtime.h>
#include <stdint.h>

#define N_NODES 50000
#define N_EDGES 800000
#define D 128
#define DOUT 64

__host__ __device__ inline uint32_t rotl32(uint32_t v, int d) {
    return (v << d) | (v >> (32 - d));
}

// JAX threefry2x32 (20 rounds), matches jax/_src/prng.py
__host__ __device__ inline void threefry2x32(uint32_t k0, uint32_t k1,
                                             uint32_t x0, uint32_t x1,
                                             uint32_t& o0, uint32_t& o1) {
    uint32_t ks2 = 0x1BD11BDAu ^ k0 ^ k1;
    x0 += k0; x1 += k1;
#define TFR(d) { x0 += x1; x1 = rotl32(x1, d); x1 ^= x0; }
    TFR(13) TFR(15) TFR(26) TFR(6)
    x0 += k1;  x1 += ks2 + 1u;
    TFR(17) TFR(29) TFR(16) TFR(24)
    x0 += ks2; x1 += k0 + 2u;
    TFR(13) TFR(15) TFR(26) TFR(6)
    x0 += k0;  x1 += k1 + 3u;
    TFR(17) TFR(29) TFR(16) TFR(24)
    x0 += k1;  x1 += ks2 + 4u;
    TFR(13) TFR(15) TFR(26) TFR(6)
    x0 += ks2; x1 += k0 + 5u;
#undef TFR
    o0 = x0; o1 = x1;
}

// partitionable random_bits(32) for flat index j: bits = x0^x1 of threefry(key,(0,j))
__device__ inline bool keep_mask(uint32_t k0, uint32_t k1, uint32_t j) {
    uint32_t b0, b1;
    threefry2x32(k0, k1, 0u, j, b0, b1);
    uint32_t bits = b0 ^ b1;
    float u = __uint_as_float((bits >> 9) | 0x3f800000u) - 1.0f;
    return u < 0.5f;
}

// float4-vectorized dropout
__global__ void drop4_kernel(const float* __restrict__ x, float* __restrict__ y,
                             uint32_t k0, uint32_t k1, int n4) {
    int t = blockIdx.x * blockDim.x + threadIdx.x;
    if (t < n4) {
        float4 v = ((const float4*)x)[t];
        uint32_t j = (uint32_t)t * 4u;
        v.x = keep_mask(k0, k1, j + 0u) ? v.x * 2.f : 0.f;
        v.y = keep_mask(k0, k1, j + 1u) ? v.y * 2.f : 0.f;
        v.z = keep_mask(k0, k1, j + 2u) ? v.z * 2.f : 0.f;
        v.w = keep_mask(k0, k1, j + 3u) ? v.w * 2.f : 0.f;
        ((float4*)y)[t] = v;
    }
}

// ---------------- CSR build ----------------

__global__ void hist_kernel(const int* __restrict__ rows, int* __restrict__ deg) {
    int e = blockIdx.x * blockDim.x + threadIdx.x;
    if (e < N_EDGES) {
        int r = rows[e];
        if (r >= 0 && r < N_NODES) atomicAdd(&deg[r], 1);
    }
}

#define SCAN_T 1024
__global__ __launch_bounds__(SCAN_T) void scan_kernel(const int* __restrict__ deg,
                                                      int* __restrict__ start,
                                                      int* __restrict__ cursor) {
    __shared__ int sums[SCAN_T];
    int tid = threadIdx.x;
    const int per = (N_NODES + SCAN_T - 1) / SCAN_T;  // 49
    int base = tid * per;
    int s = 0;
    for (int i = 0; i < per; ++i) {
        int idx = base + i;
        if (idx < N_NODES) s += deg[idx];
    }
    sums[tid] = s;
    __syncthreads();
    for (int off = 1; off < SCAN_T; off <<= 1) {
        int v = (tid >= off) ? sums[tid - off] : 0;
        __syncthreads();
        if (tid >= off) sums[tid] += v;
        __syncthreads();
    }
    int run = (tid == 0) ? 0 : sums[tid - 1];
    for (int i = 0; i < per; ++i) {
        int idx = base + i;
        if (idx < N_NODES) {
            int d = deg[idx];          // read BEFORE writes (alias-safe)
            start[idx] = run;
            cursor[idx] = run;
            run += d;
        }
    }
    if (tid == SCAN_T - 1) start[N_NODES] = sums[SCAN_T - 1];
}

__global__ void scatter_kernel(const int* __restrict__ rows, const int* __restrict__ cols,
                               const float* __restrict__ w, int* __restrict__ cursor,
                               int* __restrict__ ecol, float* __restrict__ ew) {
    int e = blockIdx.x * blockDim.x + threadIdx.x;
    if (e < N_EDGES) {
        int r = rows[e];
        if (r < 0 || r >= N_NODES) return;            // defensive
        int pos = atomicAdd(&cursor[r], 1);
        if (pos < 0 || pos >= N_EDGES) return;        // defensive: never write OOB
        ecol[pos] = cols[e];
        ew[pos] = w[e];
    }
}

// ---------------- SpMM (CSR, gather) ----------------
__global__ __launch_bounds__(256) void spmm_csr(const int* __restrict__ start,
                                                const int* __restrict__ ecol,
                                                const float* __restrict__ ew,
                                                const float* __restrict__ h,
                                                float* __restrict__ out) {
    int t = blockIdx.x * blockDim.x + threadIdx.x;
    int r = t >> 5;
    if (r >= N_NODES) return;
    int lane = t & 31;
    int s0 = start[r], s1 = start[r + 1];
    float4 acc = make_float4(0.f, 0.f, 0.f, 0.f);
    for (int i = s0; i < s1; ++i) {
        int c = ecol[i];
        float we = ew[i];
        float4 v = ((const float4*)(h + (size_t)c * D))[lane];
        acc.x += we * v.x;
        acc.y += we * v.y;
        acc.z += we * v.z;
        acc.w += we * v.w;
    }
    ((float4*)(out + (size_t)r * D))[lane] = acc;
}

// ---------------- lin1: out = dropout(relu(s @ W1 + b1)) ----------------
// 32-row tile in LDS (16KB); W1 from global (L1/L2-hot); 4x4 register tile.
__global__ __launch_bounds__(256) void lin1_v2(const float* __restrict__ s,
                                               const float* __restrict__ W1,
                                               const float* __restrict__ b1,
                                               float* __restrict__ out,
                                               uint32_t k0, uint32_t k1) {
    __shared__ float st[32][128];  // 16 KB
    int rowBase = blockIdx.x * 32;
    for (int i = threadIdx.x; i < 1024; i += 256) {
        int rr = i >> 5;
        int c4 = i & 31;
        int row = rowBase + rr;
        float4 v = (row < N_NODES) ? ((const float4*)(s + (size_t)row * 128))[c4]
                                   : make_float4(0.f, 0.f, 0.f, 0.f);
        *((float4*)&st[rr][c4 * 4]) = v;
    }
    __syncthreads();

    int cg = threadIdx.x & 31;   // 32 col groups: c0 = 0..124
    int rg = threadIdx.x >> 5;   // 8 row groups:  r0 = 0..28
    int c0 = cg * 4;
    int r0 = rg * 4;

    float acc[4][4] = {{0.f}};
#pragma unroll 8
    for (int k = 0; k < 128; ++k) {
        float4 wv = *(const float4*)(W1 + ((size_t)k << 7) + c0);
#pragma unroll
        for (int i = 0; i < 4; ++i) {
            float sv = st[r0 + i][k];
            acc[i][0] = fmaf(sv, wv.x, acc[i][0]);
            acc[i][1] = fmaf(sv, wv.y, acc[i][1]);
            acc[i][2] = fmaf(sv, wv.z, acc[i][2]);
            acc[i][3] = fmaf(sv, wv.w, acc[i][3]);
        }
    }

    float4 bias = *(const float4*)(b1 + c0);
#pragma unroll
    for (int i = 0; i < 4; ++i) {
        int row = rowBase + r0 + i;
        if (row >= N_NODES) continue;
        float4 o;
        o.x = fmaxf(acc[i][0] + bias.x, 0.f);
        o.y = fmaxf(acc[i][1] + bias.y, 0.f);
        o.z = fmaxf(acc[i][2] + bias.z, 0.f);
        o.w = fmaxf(acc[i][3] + bias.w, 0.f);
        uint32_t j = (uint32_t)row * 128u + (uint32_t)c0;
        o.x = keep_mask(k0, k1, j + 0u) ? o.x * 2.f : 0.f;
        o.y = keep_mask(k0, k1, j + 1u) ? o.y * 2.f : 0.f;
        o.z = keep_mask(k0, k1, j + 2u) ? o.z * 2.f : 0.f;
        o.w = keep_mask(k0, k1, j + 3u) ? o.w * 2.f : 0.f;
        *(float4*)(out + (size_t)row * 128 + c0) = o;
    }
}

// ---------------- lin2: out = s @ W2 + b2 ----------------
// 64-row tile in LDS (32KB); W2 from global; 4x4 register tile.
__global__ __launch_bounds__(256) void lin2_v2(const float* __restrict__ s,
                                               const float* __restrict__ W2,
                                               const float* __restrict__ b2,
                                               float* __restrict__ out) {
    __shared__ float st[64][128];  // 32 KB
    int rowBase = blockIdx.x * 64;
    for (int i = threadIdx.x; i < 2048; i += 256) {
        int rr = i >> 5;
        int c4 = i & 31;
        int row = rowBase + rr;
        float4 v = (row < N_NODES) ? ((const float4*)(s + (size_t)row * 128))[c4]
                                   : make_float4(0.f, 0.f, 0.f, 0.f);
        *((float4*)&st[rr][c4 * 4]) = v;
    }
    __syncthreads();

    int cg = threadIdx.x & 15;   // 16 col groups: c0 = 0..60
    int rg = threadIdx.x >> 4;   // 16 row groups: r0 = 0..60
    int c0 = cg * 4;
    int r0 = rg * 4;

    float acc[4][4] = {{0.f}};
#pragma unroll 8
    for (int k = 0; k < 128; ++k) {
        float4 wv = *(const float4*)(W2 + ((size_t)k << 6) + c0);
#pragma unroll
        for (int i = 0; i < 4; ++i) {
            float sv = st[r0 + i][k];
            acc[i][0] = fmaf(sv, wv.x, acc[i][0]);
            acc[i][1] = fmaf(sv, wv.y, acc[i][1]);
            acc[i][2] = fmaf(sv, wv.z, acc[i][2]);
            acc[i][3] = fmaf(sv, wv.w, acc[i][3]);
        }
    }

    float4 bias = *(const float4*)(b2 + c0);
#pragma unroll
    for (int i = 0; i < 4; ++i) {
        int row = rowBase + r0 + i;
        if (row >= N_NODES) continue;
        float4 o;
        o.x = acc[i][0] + bias.x;
        o.y = acc[i][1] + bias.y;
        o.z = acc[i][2] + bias.z;
        o.w = acc[i][3] + bias.w;
        *(float4*)(out + (size_t)row * DOUT + c0) = o;
    }
}

extern "C" void kernel_launch(void* const* d_in, const int* in_sizes, int n_in,
                              void* d_out, int out_size, void* d_ws, size_t ws_size,
                              hipStream_t stream) {
    const int*   rows = (const int*)d_in[0];
    const int*   cols = (const int*)d_in[1];
    const float* w    = (const float*)d_in[2];
    const float* X    = (const float*)d_in[3];
    const float* W1   = (const float*)d_in[4];
    const float* b1   = (const float*)d_in[5];
    const float* W2   = (const float*)d_in[6];
    const float* b2   = (const float*)d_in[7];
    float* out = (float*)d_out;

    size_t matBytes = (size_t)N_NODES * D * sizeof(float);  // 25.6 MB

    // Host-side key derivation: split(key(42)) under threefry-partitionable
    uint32_t ka0, ka1, kb0, kb1;
    threefry2x32(0u, 42u, 0u, 0u, ka0, ka1);  // k1 (drop1)
    threefry2x32(0u, 42u, 0u, 1u, kb0, kb1);  // k2 (drop2)

    int n4 = N_NODES * D / 4;  // 1.6M float4s

    // workspace layout (all buffers distinct — NO aliasing)
    char* p = (char*)d_ws;
    float* A      = (float*)p;                 p += matBytes;
    float* B      = (float*)p;                 p += matBytes;
    int*   ecol   = (int*)p;                   p += (size_t)N_EDGES * 4;
    float* ew     = (float*)p;                 p += (size_t)N_EDGES * 4;
    int*   start  = (int*)p;                   p += (size_t)(N_NODES + 1) * 4;
    int*   cursor = (int*)p;                   p += (size_t)N_NODES * 4;
    int*   deg    = (int*)p;                   p += (size_t)N_NODES * 4;
    size_t needed = (size_t)(p - (char*)d_ws);
    (void)needed;

    // ---- CSR build ----
    hipMemsetAsync(deg, 0, (size_t)N_NODES * 4, stream);
    hist_kernel<<<(N_EDGES + 255) / 256, 256, 0, stream>>>(rows, deg);
    scan_kernel<<<1, SCAN_T, 0, stream>>>(deg, start, cursor);
    scatter_kernel<<<(N_EDGES + 255) / 256, 256, 0, stream>>>(rows, cols, w, cursor, ecol, ew);

    // ---- forward ----
    drop4_kernel<<<(n4 + 255) / 256, 256, 0, stream>>>(X, A, ka0, ka1, n4);
    spmm_csr<<<((size_t)N_NODES * 32 + 255) / 256, 256, 0, stream>>>(start, ecol, ew, A, B);
    lin1_v2<<<(N_NODES + 31) / 32, 256, 0, stream>>>(B, W1, b1, A, kb0, kb1);
    spmm_csr<<<((size_t)N_NODES * 32 + 255) / 256, 256, 0, stream>>>(start, ecol, ew, A, B);
    lin2_v2<<<(N_NODES + 63) / 64, 256, 0, stream>>>(B, W2, b2, out);
}

// Round 7
// 312.873 us; speedup vs baseline: 9.4758x; 1.3691x over previous
//
#include <hip/hip_runtime.h>
#include <stdint.h>

#define N_NODES 50000
#define N_EDGES 800000
#define D 128
#define DOUT 64

#define CSR_BLK 256
#define CSR_NBLK ((N_NODES + CSR_BLK - 1) / CSR_BLK)  // 196

__host__ __device__ inline uint32_t rotl32(uint32_t v, int d) {
    return (v << d) | (v >> (32 - d));
}

// JAX threefry2x32 (20 rounds), matches jax/_src/prng.py
__host__ __device__ inline void threefry2x32(uint32_t k0, uint32_t k1,
                                             uint32_t x0, uint32_t x1,
                                             uint32_t& o0, uint32_t& o1) {
    uint32_t ks2 = 0x1BD11BDAu ^ k0 ^ k1;
    x0 += k0; x1 += k1;
#define TFR(d) { x0 += x1; x1 = rotl32(x1, d); x1 ^= x0; }
    TFR(13) TFR(15) TFR(26) TFR(6)
    x0 += k1;  x1 += ks2 + 1u;
    TFR(17) TFR(29) TFR(16) TFR(24)
    x0 += ks2; x1 += k0 + 2u;
    TFR(13) TFR(15) TFR(26) TFR(6)
    x0 += k0;  x1 += k1 + 3u;
    TFR(17) TFR(29) TFR(16) TFR(24)
    x0 += k1;  x1 += ks2 + 4u;
    TFR(13) TFR(15) TFR(26) TFR(6)
    x0 += ks2; x1 += k0 + 5u;
#undef TFR
    o0 = x0; o1 = x1;
}

// partitionable random_bits(32) for flat index j: bits = x0^x1 of threefry(key,(0,j))
__device__ inline bool keep_mask(uint32_t k0, uint32_t k1, uint32_t j) {
    uint32_t b0, b1;
    threefry2x32(k0, k1, 0u, j, b0, b1);
    uint32_t bits = b0 ^ b1;
    float u = __uint_as_float((bits >> 9) | 0x3f800000u) - 1.0f;
    return u < 0.5f;
}

// float4-vectorized dropout
__global__ void drop4_kernel(const float* __restrict__ x, float* __restrict__ y,
                             uint32_t k0, uint32_t k1, int n4) {
    int t = blockIdx.x * blockDim.x + threadIdx.x;
    if (t < n4) {
        float4 v = ((const float4*)x)[t];
        uint32_t j = (uint32_t)t * 4u;
        v.x = keep_mask(k0, k1, j + 0u) ? v.x * 2.f : 0.f;
        v.y = keep_mask(k0, k1, j + 1u) ? v.y * 2.f : 0.f;
        v.z = keep_mask(k0, k1, j + 2u) ? v.z * 2.f : 0.f;
        v.w = keep_mask(k0, k1, j + 3u) ? v.w * 2.f : 0.f;
        ((float4*)y)[t] = v;
    }
}

// ---------------- CSR build ----------------

__global__ void hist_kernel(const int* __restrict__ rows, int* __restrict__ deg) {
    int e = blockIdx.x * blockDim.x + threadIdx.x;
    if (e < N_EDGES) {
        int r = rows[e];
        if (r >= 0 && r < N_NODES) atomicAdd(&deg[r], 1);
    }
}

// Phase A: per-block degree sums (196 blocks x 256)
__global__ __launch_bounds__(CSR_BLK) void degsum_kernel(const int* __restrict__ deg,
                                                         int* __restrict__ blockSums) {
    __shared__ int red[CSR_BLK];
    int idx = blockIdx.x * CSR_BLK + threadIdx.x;
    red[threadIdx.x] = (idx < N_NODES) ? deg[idx] : 0;
    __syncthreads();
    for (int off = CSR_BLK / 2; off > 0; off >>= 1) {
        if (threadIdx.x < off) red[threadIdx.x] += red[threadIdx.x + off];
        __syncthreads();
    }
    if (threadIdx.x == 0) blockSums[blockIdx.x] = red[0];
}

// Phase B: scan the 196 block sums (single small block)
__global__ __launch_bounds__(256) void scanblk_kernel(const int* __restrict__ blockSums,
                                                      int* __restrict__ blockOff) {
    __shared__ int s[256];
    int tid = threadIdx.x;
    s[tid] = (tid < CSR_NBLK) ? blockSums[tid] : 0;
    __syncthreads();
    for (int off = 1; off < 256; off <<= 1) {
        int t = (tid >= off) ? s[tid - off] : 0;
        __syncthreads();
        if (tid >= off) s[tid] += t;
        __syncthreads();
    }
    if (tid < CSR_NBLK) blockOff[tid] = (tid == 0) ? 0 : s[tid - 1];
}

// Phase C: per-block exclusive scan + block offset -> start, cursor
__global__ __launch_bounds__(CSR_BLK) void scanfinal_kernel(const int* __restrict__ deg,
                                                            const int* __restrict__ blockOff,
                                                            int* __restrict__ start,
                                                            int* __restrict__ cursor) {
    __shared__ int s[CSR_BLK];
    int tid = threadIdx.x;
    int idx = blockIdx.x * CSR_BLK + tid;
    int d = (idx < N_NODES) ? deg[idx] : 0;
    s[tid] = d;
    __syncthreads();
    for (int off = 1; off < CSR_BLK; off <<= 1) {
        int t = (tid >= off) ? s[tid - off] : 0;
        __syncthreads();
        if (tid >= off) s[tid] += t;
        __syncthreads();
    }
    int incl = s[tid];
    int excl = incl - d;
    int boff = blockOff[blockIdx.x];
    if (idx < N_NODES) {
        start[idx] = boff + excl;
        cursor[idx] = boff + excl;
        if (idx == N_NODES - 1) start[N_NODES] = boff + incl;
    }
}

__global__ void scatter_kernel(const int* __restrict__ rows, const int* __restrict__ cols,
                               const float* __restrict__ w, int* __restrict__ cursor,
                               int* __restrict__ ecol, float* __restrict__ ew) {
    int e = blockIdx.x * blockDim.x + threadIdx.x;
    if (e < N_EDGES) {
        int r = rows[e];
        if (r < 0 || r >= N_NODES) return;            // defensive
        int pos = atomicAdd(&cursor[r], 1);
        if (pos < 0 || pos >= N_EDGES) return;        // defensive: never write OOB
        ecol[pos] = cols[e];
        ew[pos] = w[e];
    }
}

// ---------------- SpMM (CSR, gather) ----------------
__global__ __launch_bounds__(256) void spmm_csr(const int* __restrict__ start,
                                                const int* __restrict__ ecol,
                                                const float* __restrict__ ew,
                                                const float* __restrict__ h,
                                                float* __restrict__ out) {
    int t = blockIdx.x * blockDim.x + threadIdx.x;
    int r = t >> 5;
    if (r >= N_NODES) return;
    int lane = t & 31;
    int s0 = start[r], s1 = start[r + 1];
    float4 acc = make_float4(0.f, 0.f, 0.f, 0.f);
    for (int i = s0; i < s1; ++i) {
        int c = ecol[i];
        float we = ew[i];
        float4 v = ((const float4*)(h + (size_t)c * D))[lane];
        acc.x += we * v.x;
        acc.y += we * v.y;
        acc.z += we * v.z;
        acc.w += we * v.w;
    }
    ((float4*)(out + (size_t)r * D))[lane] = acc;
}

// ---------------- lin1: out = dropout(relu(s @ W1 + b1)) ----------------
__global__ __launch_bounds__(256) void lin1_v2(const float* __restrict__ s,
                                               const float* __restrict__ W1,
                                               const float* __restrict__ b1,
                                               float* __restrict__ out,
                                               uint32_t k0, uint32_t k1) {
    __shared__ float st[32][128];  // 16 KB
    int rowBase = blockIdx.x * 32;
    for (int i = threadIdx.x; i < 1024; i += 256) {
        int rr = i >> 5;
        int c4 = i & 31;
        int row = rowBase + rr;
        float4 v = (row < N_NODES) ? ((const float4*)(s + (size_t)row * 128))[c4]
                                   : make_float4(0.f, 0.f, 0.f, 0.f);
        *((float4*)&st[rr][c4 * 4]) = v;
    }
    __syncthreads();

    int cg = threadIdx.x & 31;
    int rg = threadIdx.x >> 5;
    int c0 = cg * 4;
    int r0 = rg * 4;

    float acc[4][4] = {{0.f}};
#pragma unroll 8
    for (int k = 0; k < 128; ++k) {
        float4 wv = *(const float4*)(W1 + ((size_t)k << 7) + c0);
#pragma unroll
        for (int i = 0; i < 4; ++i) {
            float sv = st[r0 + i][k];
            acc[i][0] = fmaf(sv, wv.x, acc[i][0]);
            acc[i][1] = fmaf(sv, wv.y, acc[i][1]);
            acc[i][2] = fmaf(sv, wv.z, acc[i][2]);
            acc[i][3] = fmaf(sv, wv.w, acc[i][3]);
        }
    }

    float4 bias = *(const float4*)(b1 + c0);
#pragma unroll
    for (int i = 0; i < 4; ++i) {
        int row = rowBase + r0 + i;
        if (row >= N_NODES) continue;
        float4 o;
        o.x = fmaxf(acc[i][0] + bias.x, 0.f);
        o.y = fmaxf(acc[i][1] + bias.y, 0.f);
        o.z = fmaxf(acc[i][2] + bias.z, 0.f);
        o.w = fmaxf(acc[i][3] + bias.w, 0.f);
        uint32_t j = (uint32_t)row * 128u + (uint32_t)c0;
        o.x = keep_mask(k0, k1, j + 0u) ? o.x * 2.f : 0.f;
        o.y = keep_mask(k0, k1, j + 1u) ? o.y * 2.f : 0.f;
        o.z = keep_mask(k0, k1, j + 2u) ? o.z * 2.f : 0.f;
        o.w = keep_mask(k0, k1, j + 3u) ? o.w * 2.f : 0.f;
        *(float4*)(out + (size_t)row * 128 + c0) = o;
    }
}

// ---------------- lin2: out = s @ W2 + b2 ----------------
__global__ __launch_bounds__(256) void lin2_v2(const float* __restrict__ s,
                                               const float* __restrict__ W2,
                                               const float* __restrict__ b2,
                                               float* __restrict__ out) {
    __shared__ float st[64][128];  // 32 KB
    int rowBase = blockIdx.x * 64;
    for (int i = threadIdx.x; i < 2048; i += 256) {
        int rr = i >> 5;
        int c4 = i & 31;
        int row = rowBase + rr;
        float4 v = (row < N_NODES) ? ((const float4*)(s + (size_t)row * 128))[c4]
                                   : make_float4(0.f, 0.f, 0.f, 0.f);
        *((float4*)&st[rr][c4 * 4]) = v;
    }
    __syncthreads();

    int cg = threadIdx.x & 15;
    int rg = threadIdx.x >> 4;
    int c0 = cg * 4;
    int r0 = rg * 4;

    float acc[4][4] = {{0.f}};
#pragma unroll 8
    for (int k = 0; k < 128; ++k) {
        float4 wv = *(const float4*)(W2 + ((size_t)k << 6) + c0);
#pragma unroll
        for (int i = 0; i < 4; ++i) {
            float sv = st[r0 + i][k];
            acc[i][0] = fmaf(sv, wv.x, acc[i][0]);
            acc[i][1] = fmaf(sv, wv.y, acc[i][1]);
            acc[i][2] = fmaf(sv, wv.z, acc[i][2]);
            acc[i][3] = fmaf(sv, wv.w, acc[i][3]);
        }
    }

    float4 bias = *(const float4*)(b2 + c0);
#pragma unroll
    for (int i = 0; i < 4; ++i) {
        int row = rowBase + r0 + i;
        if (row >= N_NODES) continue;
        float4 o;
        o.x = acc[i][0] + bias.x;
        o.y = acc[i][1] + bias.y;
        o.z = acc[i][2] + bias.z;
        o.w = acc[i][3] + bias.w;
        *(float4*)(out + (size_t)row * DOUT + c0) = o;
    }
}

extern "C" void kernel_launch(void* const* d_in, const int* in_sizes, int n_in,
                              void* d_out, int out_size, void* d_ws, size_t ws_size,
                              hipStream_t stream) {
    const int*   rows = (const int*)d_in[0];
    const int*   cols = (const int*)d_in[1];
    const float* w    = (const float*)d_in[2];
    const float* X    = (const float*)d_in[3];
    const float* W1   = (const float*)d_in[4];
    const float* b1   = (const float*)d_in[5];
    const float* W2   = (const float*)d_in[6];
    const float* b2   = (const float*)d_in[7];
    float* out = (float*)d_out;

    size_t matBytes = (size_t)N_NODES * D * sizeof(float);  // 25.6 MB

    // Host-side key derivation: split(key(42)) under threefry-partitionable
    uint32_t ka0, ka1, kb0, kb1;
    threefry2x32(0u, 42u, 0u, 0u, ka0, ka1);  // k1 (drop1)
    threefry2x32(0u, 42u, 0u, 1u, kb0, kb1);  // k2 (drop2)

    int n4 = N_NODES * D / 4;  // 1.6M float4s

    // workspace layout (all buffers distinct — NO aliasing)
    char* p = (char*)d_ws;
    float* A         = (float*)p;              p += matBytes;
    float* B         = (float*)p;              p += matBytes;
    int*   ecol      = (int*)p;                p += (size_t)N_EDGES * 4;
    float* ew        = (float*)p;              p += (size_t)N_EDGES * 4;
    int*   start     = (int*)p;                p += (size_t)(N_NODES + 1) * 4;
    int*   cursor    = (int*)p;                p += (size_t)N_NODES * 4;
    int*   deg       = (int*)p;                p += (size_t)N_NODES * 4;
    int*   blockSums = (int*)p;                p += (size_t)CSR_NBLK * 4;
    int*   blockOff  = (int*)p;                p += (size_t)CSR_NBLK * 4;

    // ---- CSR build ----
    hipMemsetAsync(deg, 0, (size_t)N_NODES * 4, stream);
    hist_kernel<<<(N_EDGES + 255) / 256, 256, 0, stream>>>(rows, deg);
    degsum_kernel<<<CSR_NBLK, CSR_BLK, 0, stream>>>(deg, blockSums);
    scanblk_kernel<<<1, 256, 0, stream>>>(blockSums, blockOff);
    scanfinal_kernel<<<CSR_NBLK, CSR_BLK, 0, stream>>>(deg, blockOff, start, cursor);
    scatter_kernel<<<(N_EDGES + 255) / 256, 256, 0, stream>>>(rows, cols, w, cursor, ecol, ew);

    // ---- forward ----
    drop4_kernel<<<(n4 + 255) / 256, 256, 0, stream>>>(X, A, ka0, ka1, n4);
    spmm_csr<<<((size_t)N_NODES * 32 + 255) / 256, 256, 0, stream>>>(start, ecol, ew, A, B);
    lin1_v2<<<(N_NODES + 31) / 32, 256, 0, stream>>>(B, W1, b1, A, kb0, kb1);
    spmm_csr<<<((size_t)N_NODES * 32 + 255) / 256, 256, 0, stream>>>(start, ecol, ew, A, B);
    lin2_v2<<<(N_NODES + 63) / 64, 256, 0, stream>>>(B, W2, b2, out);
}

// Round 8
// 272.180 us; speedup vs baseline: 10.8924x; 1.1495x over previous
//
#include <hip/hip_runtime.h>
#include <stdint.h>

#define N_NODES 50000
#define N_EDGES 800000
#define D 128
#define DOUT 64

#define CSR_BLK 256
#define CSR_NBLK ((N_NODES + CSR_BLK - 1) / CSR_BLK)  // 196

__host__ __device__ inline uint32_t rotl32(uint32_t v, int d) {
    return (v << d) | (v >> (32 - d));
}

// JAX threefry2x32 (20 rounds), matches jax/_src/prng.py
__host__ __device__ inline void threefry2x32(uint32_t k0, uint32_t k1,
                                             uint32_t x0, uint32_t x1,
                                             uint32_t& o0, uint32_t& o1) {
    uint32_t ks2 = 0x1BD11BDAu ^ k0 ^ k1;
    x0 += k0; x1 += k1;
#define TFR(d) { x0 += x1; x1 = rotl32(x1, d); x1 ^= x0; }
    TFR(13) TFR(15) TFR(26) TFR(6)
    x0 += k1;  x1 += ks2 + 1u;
    TFR(17) TFR(29) TFR(16) TFR(24)
    x0 += ks2; x1 += k0 + 2u;
    TFR(13) TFR(15) TFR(26) TFR(6)
    x0 += k0;  x1 += k1 + 3u;
    TFR(17) TFR(29) TFR(16) TFR(24)
    x0 += k1;  x1 += ks2 + 4u;
    TFR(13) TFR(15) TFR(26) TFR(6)
    x0 += ks2; x1 += k0 + 5u;
#undef TFR
    o0 = x0; o1 = x1;
}

// partitionable random_bits(32) for flat index j: bits = x0^x1 of threefry(key,(0,j))
__device__ inline bool keep_mask(uint32_t k0, uint32_t k1, uint32_t j) {
    uint32_t b0, b1;
    threefry2x32(k0, k1, 0u, j, b0, b1);
    uint32_t bits = b0 ^ b1;
    float u = __uint_as_float((bits >> 9) | 0x3f800000u) - 1.0f;
    return u < 0.5f;
}

// float4-vectorized dropout
__global__ void drop4_kernel(const float* __restrict__ x, float* __restrict__ y,
                             uint32_t k0, uint32_t k1, int n4) {
    int t = blockIdx.x * blockDim.x + threadIdx.x;
    if (t < n4) {
        float4 v = ((const float4*)x)[t];
        uint32_t j = (uint32_t)t * 4u;
        v.x = keep_mask(k0, k1, j + 0u) ? v.x * 2.f : 0.f;
        v.y = keep_mask(k0, k1, j + 1u) ? v.y * 2.f : 0.f;
        v.z = keep_mask(k0, k1, j + 2u) ? v.z * 2.f : 0.f;
        v.w = keep_mask(k0, k1, j + 3u) ? v.w * 2.f : 0.f;
        ((float4*)y)[t] = v;
    }
}

// ---------------- CSR build ----------------

__global__ void hist_kernel(const int* __restrict__ rows, int* __restrict__ deg) {
    int e = blockIdx.x * blockDim.x + threadIdx.x;
    if (e < N_EDGES) {
        int r = rows[e];
        if (r >= 0 && r < N_NODES) atomicAdd(&deg[r], 1);
    }
}

// Phase A: per-block degree sums (196 blocks x 256)
__global__ __launch_bounds__(CSR_BLK) void degsum_kernel(const int* __restrict__ deg,
                                                         int* __restrict__ blockSums) {
    __shared__ int red[CSR_BLK];
    int idx = blockIdx.x * CSR_BLK + threadIdx.x;
    red[threadIdx.x] = (idx < N_NODES) ? deg[idx] : 0;
    __syncthreads();
    for (int off = CSR_BLK / 2; off > 0; off >>= 1) {
        if (threadIdx.x < off) red[threadIdx.x] += red[threadIdx.x + off];
        __syncthreads();
    }
    if (threadIdx.x == 0) blockSums[blockIdx.x] = red[0];
}

// Phase B: scan the 196 block sums (single small block)
__global__ __launch_bounds__(256) void scanblk_kernel(const int* __restrict__ blockSums,
                                                      int* __restrict__ blockOff) {
    __shared__ int s[256];
    int tid = threadIdx.x;
    s[tid] = (tid < CSR_NBLK) ? blockSums[tid] : 0;
    __syncthreads();
    for (int off = 1; off < 256; off <<= 1) {
        int t = (tid >= off) ? s[tid - off] : 0;
        __syncthreads();
        if (tid >= off) s[tid] += t;
        __syncthreads();
    }
    if (tid < CSR_NBLK) blockOff[tid] = (tid == 0) ? 0 : s[tid - 1];
}

// Phase C: per-block exclusive scan + block offset -> start, cursor
__global__ __launch_bounds__(CSR_BLK) void scanfinal_kernel(const int* __restrict__ deg,
                                                            const int* __restrict__ blockOff,
                                                            int* __restrict__ start,
                                                            int* __restrict__ cursor) {
    __shared__ int s[CSR_BLK];
    int tid = threadIdx.x;
    int idx = blockIdx.x * CSR_BLK + tid;
    int d = (idx < N_NODES) ? deg[idx] : 0;
    s[tid] = d;
    __syncthreads();
    for (int off = 1; off < CSR_BLK; off <<= 1) {
        int t = (tid >= off) ? s[tid - off] : 0;
        __syncthreads();
        if (tid >= off) s[tid] += t;
        __syncthreads();
    }
    int incl = s[tid];
    int excl = incl - d;
    int boff = blockOff[blockIdx.x];
    if (idx < N_NODES) {
        start[idx] = boff + excl;
        cursor[idx] = boff + excl;
        if (idx == N_NODES - 1) start[N_NODES] = boff + incl;
    }
}

__global__ void scatter_kernel(const int* __restrict__ rows, const int* __restrict__ cols,
                               const float* __restrict__ w, int* __restrict__ cursor,
                               int* __restrict__ ecol, float* __restrict__ ew) {
    int e = blockIdx.x * blockDim.x + threadIdx.x;
    if (e < N_EDGES) {
        int r = rows[e];
        if (r < 0 || r >= N_NODES) return;            // defensive
        int pos = atomicAdd(&cursor[r], 1);
        if (pos < 0 || pos >= N_EDGES) return;        // defensive: never write OOB
        ecol[pos] = cols[e];
        ew[pos] = w[e];
    }
}

// ---------------- SpMM 128-wide (CSR, gather, 4x unrolled for MLP) ----------------
__global__ __launch_bounds__(256) void spmm_csr(const int* __restrict__ start,
                                                const int* __restrict__ ecol,
                                                const float* __restrict__ ew,
                                                const float* __restrict__ h,
                                                float* __restrict__ out) {
    int t = blockIdx.x * blockDim.x + threadIdx.x;
    int r = t >> 5;
    if (r >= N_NODES) return;
    int lane = t & 31;
    int s0 = start[r], s1 = start[r + 1];
    float4 a0 = make_float4(0.f, 0.f, 0.f, 0.f);
    float4 a1 = a0, a2 = a0, a3 = a0;
    int i = s0;
    for (; i + 4 <= s1; i += 4) {
        int c0 = ecol[i], c1 = ecol[i + 1], c2 = ecol[i + 2], c3 = ecol[i + 3];
        float w0 = ew[i], w1 = ew[i + 1], w2 = ew[i + 2], w3 = ew[i + 3];
        float4 v0 = ((const float4*)(h + (size_t)c0 * D))[lane];
        float4 v1 = ((const float4*)(h + (size_t)c1 * D))[lane];
        float4 v2 = ((const float4*)(h + (size_t)c2 * D))[lane];
        float4 v3 = ((const float4*)(h + (size_t)c3 * D))[lane];
        a0.x = fmaf(w0, v0.x, a0.x); a0.y = fmaf(w0, v0.y, a0.y);
        a0.z = fmaf(w0, v0.z, a0.z); a0.w = fmaf(w0, v0.w, a0.w);
        a1.x = fmaf(w1, v1.x, a1.x); a1.y = fmaf(w1, v1.y, a1.y);
        a1.z = fmaf(w1, v1.z, a1.z); a1.w = fmaf(w1, v1.w, a1.w);
        a2.x = fmaf(w2, v2.x, a2.x); a2.y = fmaf(w2, v2.y, a2.y);
        a2.z = fmaf(w2, v2.z, a2.z); a2.w = fmaf(w2, v2.w, a2.w);
        a3.x = fmaf(w3, v3.x, a3.x); a3.y = fmaf(w3, v3.y, a3.y);
        a3.z = fmaf(w3, v3.z, a3.z); a3.w = fmaf(w3, v3.w, a3.w);
    }
    for (; i < s1; ++i) {
        int c = ecol[i];
        float we = ew[i];
        float4 v = ((const float4*)(h + (size_t)c * D))[lane];
        a0.x = fmaf(we, v.x, a0.x); a0.y = fmaf(we, v.y, a0.y);
        a0.z = fmaf(we, v.z, a0.z); a0.w = fmaf(we, v.w, a0.w);
    }
    float4 acc;
    acc.x = (a0.x + a1.x) + (a2.x + a3.x);
    acc.y = (a0.y + a1.y) + (a2.y + a3.y);
    acc.z = (a0.z + a1.z) + (a2.z + a3.z);
    acc.w = (a0.w + a1.w) + (a2.w + a3.w);
    ((float4*)(out + (size_t)r * D))[lane] = acc;
}

// ---------------- SpMM 64-wide + bias (for commuted lin2) ----------------
// out[r] = sum_e w[e] * t[col[e]] + b2   (16 lanes/row, float4)
__global__ __launch_bounds__(256) void spmm64_csr(const int* __restrict__ start,
                                                  const int* __restrict__ ecol,
                                                  const float* __restrict__ ew,
                                                  const float* __restrict__ t,
                                                  const float* __restrict__ b2,
                                                  float* __restrict__ out) {
    int tid = blockIdx.x * blockDim.x + threadIdx.x;
    int r = tid >> 4;
    if (r >= N_NODES) return;
    int lane = tid & 15;
    int s0 = start[r], s1 = start[r + 1];
    float4 a0 = make_float4(0.f, 0.f, 0.f, 0.f);
    float4 a1 = a0, a2 = a0, a3 = a0;
    int i = s0;
    for (; i + 4 <= s1; i += 4) {
        int c0 = ecol[i], c1 = ecol[i + 1], c2 = ecol[i + 2], c3 = ecol[i + 3];
        float w0 = ew[i], w1 = ew[i + 1], w2 = ew[i + 2], w3 = ew[i + 3];
        float4 v0 = ((const float4*)(t + (size_t)c0 * DOUT))[lane];
        float4 v1 = ((const float4*)(t + (size_t)c1 * DOUT))[lane];
        float4 v2 = ((const float4*)(t + (size_t)c2 * DOUT))[lane];
        float4 v3 = ((const float4*)(t + (size_t)c3 * DOUT))[lane];
        a0.x = fmaf(w0, v0.x, a0.x); a0.y = fmaf(w0, v0.y, a0.y);
        a0.z = fmaf(w0, v0.z, a0.z); a0.w = fmaf(w0, v0.w, a0.w);
        a1.x = fmaf(w1, v1.x, a1.x); a1.y = fmaf(w1, v1.y, a1.y);
        a1.z = fmaf(w1, v1.z, a1.z); a1.w = fmaf(w1, v1.w, a1.w);
        a2.x = fmaf(w2, v2.x, a2.x); a2.y = fmaf(w2, v2.y, a2.y);
        a2.z = fmaf(w2, v2.z, a2.z); a2.w = fmaf(w2, v2.w, a2.w);
        a3.x = fmaf(w3, v3.x, a3.x); a3.y = fmaf(w3, v3.y, a3.y);
        a3.z = fmaf(w3, v3.z, a3.z); a3.w = fmaf(w3, v3.w, a3.w);
    }
    for (; i < s1; ++i) {
        int c = ecol[i];
        float we = ew[i];
        float4 v = ((const float4*)(t + (size_t)c * DOUT))[lane];
        a0.x = fmaf(we, v.x, a0.x); a0.y = fmaf(we, v.y, a0.y);
        a0.z = fmaf(we, v.z, a0.z); a0.w = fmaf(we, v.w, a0.w);
    }
    float4 bias = ((const float4*)b2)[lane];
    float4 acc;
    acc.x = (a0.x + a1.x) + (a2.x + a3.x) + bias.x;
    acc.y = (a0.y + a1.y) + (a2.y + a3.y) + bias.y;
    acc.z = (a0.z + a1.z) + (a2.z + a3.z) + bias.z;
    acc.w = (a0.w + a1.w) + (a2.w + a3.w) + bias.w;
    ((float4*)(out + (size_t)r * DOUT))[lane] = acc;
}

// ---------------- lin1: out = dropout(relu(s @ W1 + b1)) ----------------
__global__ __launch_bounds__(256) void lin1_v2(const float* __restrict__ s,
                                               const float* __restrict__ W1,
                                               const float* __restrict__ b1,
                                               float* __restrict__ out,
                                               uint32_t k0, uint32_t k1) {
    __shared__ float st[32][128];  // 16 KB
    int rowBase = blockIdx.x * 32;
    for (int i = threadIdx.x; i < 1024; i += 256) {
        int rr = i >> 5;
        int c4 = i & 31;
        int row = rowBase + rr;
        float4 v = (row < N_NODES) ? ((const float4*)(s + (size_t)row * 128))[c4]
                                   : make_float4(0.f, 0.f, 0.f, 0.f);
        *((float4*)&st[rr][c4 * 4]) = v;
    }
    __syncthreads();

    int cg = threadIdx.x & 31;
    int rg = threadIdx.x >> 5;
    int c0 = cg * 4;
    int r0 = rg * 4;

    float acc[4][4] = {{0.f}};
#pragma unroll 8
    for (int k = 0; k < 128; ++k) {
        float4 wv = *(const float4*)(W1 + ((size_t)k << 7) + c0);
#pragma unroll
        for (int i = 0; i < 4; ++i) {
            float sv = st[r0 + i][k];
            acc[i][0] = fmaf(sv, wv.x, acc[i][0]);
            acc[i][1] = fmaf(sv, wv.y, acc[i][1]);
            acc[i][2] = fmaf(sv, wv.z, acc[i][2]);
            acc[i][3] = fmaf(sv, wv.w, acc[i][3]);
        }
    }

    float4 bias = *(const float4*)(b1 + c0);
#pragma unroll
    for (int i = 0; i < 4; ++i) {
        int row = rowBase + r0 + i;
        if (row >= N_NODES) continue;
        float4 o;
        o.x = fmaxf(acc[i][0] + bias.x, 0.f);
        o.y = fmaxf(acc[i][1] + bias.y, 0.f);
        o.z = fmaxf(acc[i][2] + bias.z, 0.f);
        o.w = fmaxf(acc[i][3] + bias.w, 0.f);
        uint32_t j = (uint32_t)row * 128u + (uint32_t)c0;
        o.x = keep_mask(k0, k1, j + 0u) ? o.x * 2.f : 0.f;
        o.y = keep_mask(k0, k1, j + 1u) ? o.y * 2.f : 0.f;
        o.z = keep_mask(k0, k1, j + 2u) ? o.z * 2.f : 0.f;
        o.w = keep_mask(k0, k1, j + 3u) ? o.w * 2.f : 0.f;
        *(float4*)(out + (size_t)row * 128 + c0) = o;
    }
}

// ---------------- lin2 (no bias): t = s @ W2 ----------------
__global__ __launch_bounds__(256) void lin2_nb(const float* __restrict__ s,
                                               const float* __restrict__ W2,
                                               float* __restrict__ t) {
    __shared__ float st[64][128];  // 32 KB
    int rowBase = blockIdx.x * 64;
    for (int i = threadIdx.x; i < 2048; i += 256) {
        int rr = i >> 5;
        int c4 = i & 31;
        int row = rowBase + rr;
        float4 v = (row < N_NODES) ? ((const float4*)(s + (size_t)row * 128))[c4]
                                   : make_float4(0.f, 0.f, 0.f, 0.f);
        *((float4*)&st[rr][c4 * 4]) = v;
    }
    __syncthreads();

    int cg = threadIdx.x & 15;
    int rg = threadIdx.x >> 4;
    int c0 = cg * 4;
    int r0 = rg * 4;

    float acc[4][4] = {{0.f}};
#pragma unroll 8
    for (int k = 0; k < 128; ++k) {
        float4 wv = *(const float4*)(W2 + ((size_t)k << 6) + c0);
#pragma unroll
        for (int i = 0; i < 4; ++i) {
            float sv = st[r0 + i][k];
            acc[i][0] = fmaf(sv, wv.x, acc[i][0]);
            acc[i][1] = fmaf(sv, wv.y, acc[i][1]);
            acc[i][2] = fmaf(sv, wv.z, acc[i][2]);
            acc[i][3] = fmaf(sv, wv.w, acc[i][3]);
        }
    }

#pragma unroll
    for (int i = 0; i < 4; ++i) {
        int row = rowBase + r0 + i;
        if (row >= N_NODES) continue;
        float4 o;
        o.x = acc[i][0];
        o.y = acc[i][1];
        o.z = acc[i][2];
        o.w = acc[i][3];
        *(float4*)(t + (size_t)row * DOUT + c0) = o;
    }
}

extern "C" void kernel_launch(void* const* d_in, const int* in_sizes, int n_in,
                              void* d_out, int out_size, void* d_ws, size_t ws_size,
                              hipStream_t stream) {
    const int*   rows = (const int*)d_in[0];
    const int*   cols = (const int*)d_in[1];
    const float* w    = (const float*)d_in[2];
    const float* X    = (const float*)d_in[3];
    const float* W1   = (const float*)d_in[4];
    const float* b1   = (const float*)d_in[5];
    const float* W2   = (const float*)d_in[6];
    const float* b2   = (const float*)d_in[7];
    float* out = (float*)d_out;

    size_t matBytes = (size_t)N_NODES * D * sizeof(float);  // 25.6 MB

    // Host-side key derivation: split(key(42)) under threefry-partitionable
    uint32_t ka0, ka1, kb0, kb1;
    threefry2x32(0u, 42u, 0u, 0u, ka0, ka1);  // k1 (drop1)
    threefry2x32(0u, 42u, 0u, 1u, kb0, kb1);  // k2 (drop2)

    int n4 = N_NODES * D / 4;  // 1.6M float4s

    // workspace layout (all buffers distinct — NO aliasing)
    char* p = (char*)d_ws;
    float* A         = (float*)p;              p += matBytes;
    float* B         = (float*)p;              p += matBytes;
    int*   ecol      = (int*)p;                p += (size_t)N_EDGES * 4;
    float* ew        = (float*)p;              p += (size_t)N_EDGES * 4;
    int*   start     = (int*)p;                p += (size_t)(N_NODES + 1) * 4;
    int*   cursor    = (int*)p;                p += (size_t)N_NODES * 4;
    int*   deg       = (int*)p;                p += (size_t)N_NODES * 4;
    int*   blockSums = (int*)p;                p += (size_t)CSR_NBLK * 4;
    int*   blockOff  = (int*)p;                p += (size_t)CSR_NBLK * 4;

    // ---- CSR build ----
    hipMemsetAsync(deg, 0, (size_t)N_NODES * 4, stream);
    hist_kernel<<<(N_EDGES + 255) / 256, 256, 0, stream>>>(rows, deg);
    degsum_kernel<<<CSR_NBLK, CSR_BLK, 0, stream>>>(deg, blockSums);
    scanblk_kernel<<<1, 256, 0, stream>>>(blockSums, blockOff);
    scanfinal_kernel<<<CSR_NBLK, CSR_BLK, 0, stream>>>(deg, blockOff, start, cursor);
    scatter_kernel<<<(N_EDGES + 255) / 256, 256, 0, stream>>>(rows, cols, w, cursor, ecol, ew);

    // ---- forward ----
    drop4_kernel<<<(n4 + 255) / 256, 256, 0, stream>>>(X, A, ka0, ka1, n4);
    spmm_csr<<<((size_t)N_NODES * 32 + 255) / 256, 256, 0, stream>>>(start, ecol, ew, A, B);
    lin1_v2<<<(N_NODES + 31) / 32, 256, 0, stream>>>(B, W1, b1, A, kb0, kb1);
    // commuted: t = A @ W2 (into B's 64-wide region), then out = spmm(t) + b2
    lin2_nb<<<(N_NODES + 63) / 64, 256, 0, stream>>>(A, W2, B);
    spmm64_csr<<<((size_t)N_NODES * 16 + 255) / 256, 256, 0, stream>>>(start, ecol, ew, B, b2, out);
}

// Round 9
// 234.527 us; speedup vs baseline: 12.6412x; 1.1606x over previous
//
#include <hip/hip_runtime.h>
#include <stdint.h>

#define N_NODES 50000
#define N_EDGES 800000
#define D 128
#define DOUT 64

#define CSR_BLK 256
#define CSR_NBLK ((N_NODES + CSR_BLK - 1) / CSR_BLK)  // 196

__host__ __device__ inline uint32_t rotl32(uint32_t v, int d) {
    return (v << d) | (v >> (32 - d));
}

// JAX threefry2x32 (20 rounds), matches jax/_src/prng.py
__host__ __device__ inline void threefry2x32(uint32_t k0, uint32_t k1,
                                             uint32_t x0, uint32_t x1,
                                             uint32_t& o0, uint32_t& o1) {
    uint32_t ks2 = 0x1BD11BDAu ^ k0 ^ k1;
    x0 += k0; x1 += k1;
#define TFR(d) { x0 += x1; x1 = rotl32(x1, d); x1 ^= x0; }
    TFR(13) TFR(15) TFR(26) TFR(6)
    x0 += k1;  x1 += ks2 + 1u;
    TFR(17) TFR(29) TFR(16) TFR(24)
    x0 += ks2; x1 += k0 + 2u;
    TFR(13) TFR(15) TFR(26) TFR(6)
    x0 += k0;  x1 += k1 + 3u;
    TFR(17) TFR(29) TFR(16) TFR(24)
    x0 += k1;  x1 += ks2 + 4u;
    TFR(13) TFR(15) TFR(26) TFR(6)
    x0 += ks2; x1 += k0 + 5u;
#undef TFR
    o0 = x0; o1 = x1;
}

// partitionable random_bits(32) for flat index j: bits = x0^x1 of threefry(key,(0,j))
__device__ inline bool keep_mask(uint32_t k0, uint32_t k1, uint32_t j) {
    uint32_t b0, b1;
    threefry2x32(k0, k1, 0u, j, b0, b1);
    uint32_t bits = b0 ^ b1;
    float u = __uint_as_float((bits >> 9) | 0x3f800000u) - 1.0f;
    return u < 0.5f;
}

// fp32 -> bf16 (round-to-nearest-even), and unpack helpers
__device__ inline uint32_t f2bf(float f) {
    uint32_t u = __float_as_uint(f);
    return (u + 0x7fffu + ((u >> 16) & 1u)) >> 16;
}
__device__ inline float bf2f_lo(uint32_t u) { return __uint_as_float(u << 16); }
__device__ inline float bf2f_hi(uint32_t u) { return __uint_as_float(u & 0xffff0000u); }

__device__ inline void fma8(float* a, uint4 u, float w) {
    a[0] = fmaf(w, bf2f_lo(u.x), a[0]);
    a[1] = fmaf(w, bf2f_hi(u.x), a[1]);
    a[2] = fmaf(w, bf2f_lo(u.y), a[2]);
    a[3] = fmaf(w, bf2f_hi(u.y), a[3]);
    a[4] = fmaf(w, bf2f_lo(u.z), a[4]);
    a[5] = fmaf(w, bf2f_hi(u.z), a[5]);
    a[6] = fmaf(w, bf2f_lo(u.w), a[6]);
    a[7] = fmaf(w, bf2f_hi(u.w), a[7]);
}

// dropout(X) -> bf16, 8 elems/thread
__global__ void drop8_kernel(const float* __restrict__ x, ushort* __restrict__ y,
                             uint32_t k0, uint32_t k1, int n8) {
    int t = blockIdx.x * blockDim.x + threadIdx.x;
    if (t >= n8) return;
    float4 v0 = ((const float4*)x)[t * 2];
    float4 v1 = ((const float4*)x)[t * 2 + 1];
    uint32_t j = (uint32_t)t * 8u;
    float f[8] = {v0.x, v0.y, v0.z, v0.w, v1.x, v1.y, v1.z, v1.w};
    uint32_t o[4];
#pragma unroll
    for (int p = 0; p < 4; ++p) {
        float a = keep_mask(k0, k1, j + 2 * p)     ? f[2 * p] * 2.f     : 0.f;
        float b = keep_mask(k0, k1, j + 2 * p + 1) ? f[2 * p + 1] * 2.f : 0.f;
        o[p] = f2bf(a) | (f2bf(b) << 16);
    }
    ((uint4*)y)[t] = make_uint4(o[0], o[1], o[2], o[3]);
}

// ---------------- CSR build ----------------

__global__ void hist_kernel(const int* __restrict__ rows, int* __restrict__ deg) {
    int e = blockIdx.x * blockDim.x + threadIdx.x;
    if (e < N_EDGES) {
        int r = rows[e];
        if (r >= 0 && r < N_NODES) atomicAdd(&deg[r], 1);
    }
}

__global__ __launch_bounds__(CSR_BLK) void degsum_kernel(const int* __restrict__ deg,
                                                         int* __restrict__ blockSums) {
    __shared__ int red[CSR_BLK];
    int idx = blockIdx.x * CSR_BLK + threadIdx.x;
    red[threadIdx.x] = (idx < N_NODES) ? deg[idx] : 0;
    __syncthreads();
    for (int off = CSR_BLK / 2; off > 0; off >>= 1) {
        if (threadIdx.x < off) red[threadIdx.x] += red[threadIdx.x + off];
        __syncthreads();
    }
    if (threadIdx.x == 0) blockSums[blockIdx.x] = red[0];
}

__global__ __launch_bounds__(256) void scanblk_kernel(const int* __restrict__ blockSums,
                                                      int* __restrict__ blockOff) {
    __shared__ int s[256];
    int tid = threadIdx.x;
    s[tid] = (tid < CSR_NBLK) ? blockSums[tid] : 0;
    __syncthreads();
    for (int off = 1; off < 256; off <<= 1) {
        int t = (tid >= off) ? s[tid - off] : 0;
        __syncthreads();
        if (tid >= off) s[tid] += t;
        __syncthreads();
    }
    if (tid < CSR_NBLK) blockOff[tid] = (tid == 0) ? 0 : s[tid - 1];
}

__global__ __launch_bounds__(CSR_BLK) void scanfinal_kernel(const int* __restrict__ deg,
                                                            const int* __restrict__ blockOff,
                                                            int* __restrict__ start,
                                                            int* __restrict__ cursor) {
    __shared__ int s[CSR_BLK];
    int tid = threadIdx.x;
    int idx = blockIdx.x * CSR_BLK + tid;
    int d = (idx < N_NODES) ? deg[idx] : 0;
    s[tid] = d;
    __syncthreads();
    for (int off = 1; off < CSR_BLK; off <<= 1) {
        int t = (tid >= off) ? s[tid - off] : 0;
        __syncthreads();
        if (tid >= off) s[tid] += t;
        __syncthreads();
    }
    int incl = s[tid];
    int excl = incl - d;
    int boff = blockOff[blockIdx.x];
    if (idx < N_NODES) {
        start[idx] = boff + excl;
        cursor[idx] = boff + excl;
        if (idx == N_NODES - 1) start[N_NODES] = boff + incl;
    }
}

// packed edge: .x = col, .y = float bits of w
__global__ void scatter_kernel(const int* __restrict__ rows, const int* __restrict__ cols,
                               const float* __restrict__ w, int* __restrict__ cursor,
                               int2* __restrict__ epk) {
    int e = blockIdx.x * blockDim.x + threadIdx.x;
    if (e < N_EDGES) {
        int r = rows[e];
        if (r < 0 || r >= N_NODES) return;            // defensive
        int pos = atomicAdd(&cursor[r], 1);
        if (pos < 0 || pos >= N_EDGES) return;        // defensive: never write OOB
        epk[pos] = make_int2(cols[e], __float_as_int(w[e]));
    }
}

// ---------------- SpMM 128-wide, bf16 gather -> fp32 out ----------------
// 16 lanes/row, uint4 (8 bf16) per lane
__global__ __launch_bounds__(256) void spmm128_bf16(const int* __restrict__ start,
                                                    const int2* __restrict__ epk,
                                                    const ushort* __restrict__ hb,
                                                    float* __restrict__ out) {
    int t = blockIdx.x * blockDim.x + threadIdx.x;
    int r = t >> 4;
    if (r >= N_NODES) return;
    int lane = t & 15;
    int s0 = start[r], s1 = start[r + 1];
    float a0[8] = {0.f, 0.f, 0.f, 0.f, 0.f, 0.f, 0.f, 0.f};
    float a1[8] = {0.f, 0.f, 0.f, 0.f, 0.f, 0.f, 0.f, 0.f};
    int i = s0;
    for (; i + 4 <= s1; i += 4) {
        int2 e0 = epk[i], e1 = epk[i + 1], e2 = epk[i + 2], e3 = epk[i + 3];
        uint4 u0 = *(const uint4*)(hb + (size_t)e0.x * D + lane * 8);
        uint4 u1 = *(const uint4*)(hb + (size_t)e1.x * D + lane * 8);
        uint4 u2 = *(const uint4*)(hb + (size_t)e2.x * D + lane * 8);
        uint4 u3 = *(const uint4*)(hb + (size_t)e3.x * D + lane * 8);
        fma8(a0, u0, __int_as_float(e0.y));
        fma8(a1, u1, __int_as_float(e1.y));
        fma8(a0, u2, __int_as_float(e2.y));
        fma8(a1, u3, __int_as_float(e3.y));
    }
    for (; i < s1; ++i) {
        int2 e = epk[i];
        uint4 u = *(const uint4*)(hb + (size_t)e.x * D + lane * 8);
        fma8(a0, u, __int_as_float(e.y));
    }
    float* op = out + (size_t)r * D + lane * 8;
    *(float4*)(op + 0) = make_float4(a0[0] + a1[0], a0[1] + a1[1], a0[2] + a1[2], a0[3] + a1[3]);
    *(float4*)(op + 4) = make_float4(a0[4] + a1[4], a0[5] + a1[5], a0[6] + a1[6], a0[7] + a1[7]);
}

// ---------------- SpMM 64-wide + bias, bf16 gather ----------------
// 8 lanes/row, uint4 (8 bf16) per lane
__global__ __launch_bounds__(256) void spmm64_bf16(const int* __restrict__ start,
                                                   const int2* __restrict__ epk,
                                                   const ushort* __restrict__ tb,
                                                   const float* __restrict__ b2,
                                                   float* __restrict__ out) {
    int t = blockIdx.x * blockDim.x + threadIdx.x;
    int r = t >> 3;
    if (r >= N_NODES) return;
    int lane = t & 7;
    int s0 = start[r], s1 = start[r + 1];
    float a0[8] = {0.f, 0.f, 0.f, 0.f, 0.f, 0.f, 0.f, 0.f};
    float a1[8] = {0.f, 0.f, 0.f, 0.f, 0.f, 0.f, 0.f, 0.f};
    int i = s0;
    for (; i + 4 <= s1; i += 4) {
        int2 e0 = epk[i], e1 = epk[i + 1], e2 = epk[i + 2], e3 = epk[i + 3];
        uint4 u0 = *(const uint4*)(tb + (size_t)e0.x * DOUT + lane * 8);
        uint4 u1 = *(const uint4*)(tb + (size_t)e1.x * DOUT + lane * 8);
        uint4 u2 = *(const uint4*)(tb + (size_t)e2.x * DOUT + lane * 8);
        uint4 u3 = *(const uint4*)(tb + (size_t)e3.x * DOUT + lane * 8);
        fma8(a0, u0, __int_as_float(e0.y));
        fma8(a1, u1, __int_as_float(e1.y));
        fma8(a0, u2, __int_as_float(e2.y));
        fma8(a1, u3, __int_as_float(e3.y));
    }
    for (; i < s1; ++i) {
        int2 e = epk[i];
        uint4 u = *(const uint4*)(tb + (size_t)e.x * DOUT + lane * 8);
        fma8(a0, u, __int_as_float(e.y));
    }
    float4 blo = *(const float4*)(b2 + lane * 8);
    float4 bhi = *(const float4*)(b2 + lane * 8 + 4);
    float* op = out + (size_t)r * DOUT + lane * 8;
    *(float4*)(op + 0) = make_float4(a0[0] + a1[0] + blo.x, a0[1] + a1[1] + blo.y,
                                     a0[2] + a1[2] + blo.z, a0[3] + a1[3] + blo.w);
    *(float4*)(op + 4) = make_float4(a0[4] + a1[4] + bhi.x, a0[5] + a1[5] + bhi.y,
                                     a0[6] + a1[6] + bhi.z, a0[7] + a1[7] + bhi.w);
}

// ---------------- fused lin1+lin2: t = (dropout(relu(s@W1+b1))) @ W2, bf16 out ----------------
#define PAD 132
__global__ __launch_bounds__(256) void lin12_kernel(const float* __restrict__ s,
                                                    const float* __restrict__ W1,
                                                    const float* __restrict__ b1,
                                                    const float* __restrict__ W2,
                                                    ushort* __restrict__ tout,
                                                    uint32_t k0, uint32_t k1) {
    __shared__ float st[32][PAD];  // input tile
    __shared__ float h1[32][PAD];  // hidden tile
    int rowBase = blockIdx.x * 32;
    for (int i = threadIdx.x; i < 1024; i += 256) {
        int rr = i >> 5;
        int c4 = i & 31;
        int row = rowBase + rr;
        float4 v = (row < N_NODES) ? ((const float4*)(s + (size_t)row * 128))[c4]
                                   : make_float4(0.f, 0.f, 0.f, 0.f);
        *((float4*)&st[rr][c4 * 4]) = v;
    }
    __syncthreads();

    // GEMM1: 32x128 @ 128x128, 4x4 per thread
    {
        int cg = threadIdx.x & 31;
        int rg = threadIdx.x >> 5;
        int c0 = cg * 4;
        int r0 = rg * 4;
        float acc[4][4] = {{0.f}};
#pragma unroll 8
        for (int k = 0; k < 128; ++k) {
            float4 wv = *(const float4*)(W1 + ((size_t)k << 7) + c0);
#pragma unroll
            for (int i = 0; i < 4; ++i) {
                float sv = st[r0 + i][k];
                acc[i][0] = fmaf(sv, wv.x, acc[i][0]);
                acc[i][1] = fmaf(sv, wv.y, acc[i][1]);
                acc[i][2] = fmaf(sv, wv.z, acc[i][2]);
                acc[i][3] = fmaf(sv, wv.w, acc[i][3]);
            }
        }
        float4 bias = *(const float4*)(b1 + c0);
#pragma unroll
        for (int i = 0; i < 4; ++i) {
            int row = rowBase + r0 + i;
            float4 o;
            o.x = fmaxf(acc[i][0] + bias.x, 0.f);
            o.y = fmaxf(acc[i][1] + bias.y, 0.f);
            o.z = fmaxf(acc[i][2] + bias.z, 0.f);
            o.w = fmaxf(acc[i][3] + bias.w, 0.f);
            uint32_t j = (uint32_t)row * 128u + (uint32_t)c0;
            o.x = keep_mask(k0, k1, j + 0u) ? o.x * 2.f : 0.f;
            o.y = keep_mask(k0, k1, j + 1u) ? o.y * 2.f : 0.f;
            o.z = keep_mask(k0, k1, j + 2u) ? o.z * 2.f : 0.f;
            o.w = keep_mask(k0, k1, j + 3u) ? o.w * 2.f : 0.f;
            *((float4*)&h1[r0 + i][c0]) = o;
        }
    }
    __syncthreads();

    // GEMM2: 32x128 @ 128x64, 2 rows x 4 cols per thread, bf16 out
    {
        int cg = threadIdx.x & 15;
        int rg = threadIdx.x >> 4;
        int c0 = cg * 4;
        int r0 = rg * 2;
        float acc[2][4] = {{0.f}};
#pragma unroll 8
        for (int k = 0; k < 128; ++k) {
            float4 wv = *(const float4*)(W2 + ((size_t)k << 6) + c0);
#pragma unroll
            for (int i = 0; i < 2; ++i) {
                float sv = h1[r0 + i][k];
                acc[i][0] = fmaf(sv, wv.x, acc[i][0]);
                acc[i][1] = fmaf(sv, wv.y, acc[i][1]);
                acc[i][2] = fmaf(sv, wv.z, acc[i][2]);
                acc[i][3] = fmaf(sv, wv.w, acc[i][3]);
            }
        }
#pragma unroll
        for (int i = 0; i < 2; ++i) {
            int row = rowBase + r0 + i;
            if (row >= N_NODES) continue;
            uint32_t lo = f2bf(acc[i][0]) | (f2bf(acc[i][1]) << 16);
            uint32_t hi = f2bf(acc[i][2]) | (f2bf(acc[i][3]) << 16);
            *(uint2*)(tout + (size_t)row * DOUT + c0) = make_uint2(lo, hi);
        }
    }
}

extern "C" void kernel_launch(void* const* d_in, const int* in_sizes, int n_in,
                              void* d_out, int out_size, void* d_ws, size_t ws_size,
                              hipStream_t stream) {
    const int*   rows = (const int*)d_in[0];
    const int*   cols = (const int*)d_in[1];
    const float* w    = (const float*)d_in[2];
    const float* X    = (const float*)d_in[3];
    const float* W1   = (const float*)d_in[4];
    const float* b1   = (const float*)d_in[5];
    const float* W2   = (const float*)d_in[6];
    const float* b2   = (const float*)d_in[7];
    float* out = (float*)d_out;

    // Host-side key derivation: split(key(42)) under threefry-partitionable
    uint32_t ka0, ka1, kb0, kb1;
    threefry2x32(0u, 42u, 0u, 0u, ka0, ka1);  // k1 (drop1)
    threefry2x32(0u, 42u, 0u, 1u, kb0, kb1);  // k2 (drop2)

    // workspace layout (16B-aligned blocks, no aliasing)
    char* p = (char*)d_ws;
    float*  B         = (float*)p;             p += (size_t)N_NODES * D * 4;      // 25.6 MB
    ushort* Xb        = (ushort*)p;            p += (size_t)N_NODES * D * 2;      // 12.8 MB
    ushort* T         = (ushort*)p;            p += (size_t)N_NODES * DOUT * 2;   // 6.4 MB
    int2*   epk       = (int2*)p;              p += (size_t)N_EDGES * 8;          // 6.4 MB
    int*    start     = (int*)p;               p += (size_t)(N_NODES + 1) * 4;
    int*    cursor    = (int*)p;               p += (size_t)N_NODES * 4;
    int*    deg       = (int*)p;               p += (size_t)N_NODES * 4;
    int*    blockSums = (int*)p;               p += (size_t)CSR_NBLK * 4;
    int*    blockOff  = (int*)p;               p += (size_t)CSR_NBLK * 4;

    // ---- CSR build ----
    hipMemsetAsync(deg, 0, (size_t)N_NODES * 4, stream);
    hist_kernel<<<(N_EDGES + 255) / 256, 256, 0, stream>>>(rows, deg);
    degsum_kernel<<<CSR_NBLK, CSR_BLK, 0, stream>>>(deg, blockSums);
    scanblk_kernel<<<1, 256, 0, stream>>>(blockSums, blockOff);
    scanfinal_kernel<<<CSR_NBLK, CSR_BLK, 0, stream>>>(deg, blockOff, start, cursor);
    scatter_kernel<<<(N_EDGES + 255) / 256, 256, 0, stream>>>(rows, cols, w, cursor, epk);

    // ---- forward ----
    int n8 = N_NODES * D / 8;  // 800000
    drop8_kernel<<<(n8 + 255) / 256, 256, 0, stream>>>(X, Xb, ka0, ka1, n8);
    spmm128_bf16<<<((size_t)N_NODES * 16 + 255) / 256, 256, 0, stream>>>(start, epk, Xb, B);
    lin12_kernel<<<(N_NODES + 31) / 32, 256, 0, stream>>>(B, W1, b1, W2, T, kb0, kb1);
    spmm64_bf16<<<((size_t)N_NODES * 8 + 255) / 256, 256, 0, stream>>>(start, epk, T, b2, out);
}

// Round 10
// 200.889 us; speedup vs baseline: 14.7579x; 1.1674x over previous
//
#include <hip/hip_runtime.h>
#include <stdint.h>

#define N_NODES 50000
#define N_EDGES 800000
#define D 128
#define DOUT 64

#define CSR_BLK 256
#define CSR_NBLK ((N_NODES + CSR_BLK - 1) / CSR_BLK)  // 196

typedef short bf16x8 __attribute__((ext_vector_type(8)));
typedef float f32x4 __attribute__((ext_vector_type(4)));

__host__ __device__ inline uint32_t rotl32(uint32_t v, int d) {
    return (v << d) | (v >> (32 - d));
}

// JAX threefry2x32 (20 rounds), matches jax/_src/prng.py
__host__ __device__ inline void threefry2x32(uint32_t k0, uint32_t k1,
                                             uint32_t x0, uint32_t x1,
                                             uint32_t& o0, uint32_t& o1) {
    uint32_t ks2 = 0x1BD11BDAu ^ k0 ^ k1;
    x0 += k0; x1 += k1;
#define TFR(d) { x0 += x1; x1 = rotl32(x1, d); x1 ^= x0; }
    TFR(13) TFR(15) TFR(26) TFR(6)
    x0 += k1;  x1 += ks2 + 1u;
    TFR(17) TFR(29) TFR(16) TFR(24)
    x0 += ks2; x1 += k0 + 2u;
    TFR(13) TFR(15) TFR(26) TFR(6)
    x0 += k0;  x1 += k1 + 3u;
    TFR(17) TFR(29) TFR(16) TFR(24)
    x0 += k1;  x1 += ks2 + 4u;
    TFR(13) TFR(15) TFR(26) TFR(6)
    x0 += ks2; x1 += k0 + 5u;
#undef TFR
    o0 = x0; o1 = x1;
}

// partitionable random_bits(32) for flat index j: bits = x0^x1 of threefry(key,(0,j))
__device__ inline bool keep_mask(uint32_t k0, uint32_t k1, uint32_t j) {
    uint32_t b0, b1;
    threefry2x32(k0, k1, 0u, j, b0, b1);
    uint32_t bits = b0 ^ b1;
    float u = __uint_as_float((bits >> 9) | 0x3f800000u) - 1.0f;
    return u < 0.5f;
}

// fp32 -> bf16 (round-to-nearest-even), and unpack helpers
__device__ inline uint32_t f2bf(float f) {
    uint32_t u = __float_as_uint(f);
    return (u + 0x7fffu + ((u >> 16) & 1u)) >> 16;
}
__device__ inline float bf2f_lo(uint32_t u) { return __uint_as_float(u << 16); }
__device__ inline float bf2f_hi(uint32_t u) { return __uint_as_float(u & 0xffff0000u); }

__device__ inline void fma8(float* a, uint4 u, float w) {
    a[0] = fmaf(w, bf2f_lo(u.x), a[0]);
    a[1] = fmaf(w, bf2f_hi(u.x), a[1]);
    a[2] = fmaf(w, bf2f_lo(u.y), a[2]);
    a[3] = fmaf(w, bf2f_hi(u.y), a[3]);
    a[4] = fmaf(w, bf2f_lo(u.z), a[4]);
    a[5] = fmaf(w, bf2f_hi(u.z), a[5]);
    a[6] = fmaf(w, bf2f_lo(u.w), a[6]);
    a[7] = fmaf(w, bf2f_hi(u.w), a[7]);
}

// dropout(X) -> bf16, 8 elems/thread
__global__ void drop8_kernel(const float* __restrict__ x, ushort* __restrict__ y,
                             uint32_t k0, uint32_t k1, int n8) {
    int t = blockIdx.x * blockDim.x + threadIdx.x;
    if (t >= n8) return;
    float4 v0 = ((const float4*)x)[t * 2];
    float4 v1 = ((const float4*)x)[t * 2 + 1];
    uint32_t j = (uint32_t)t * 8u;
    float f[8] = {v0.x, v0.y, v0.z, v0.w, v1.x, v1.y, v1.z, v1.w};
    uint32_t o[4];
#pragma unroll
    for (int p = 0; p < 4; ++p) {
        float a = keep_mask(k0, k1, j + 2 * p)     ? f[2 * p] * 2.f     : 0.f;
        float b = keep_mask(k0, k1, j + 2 * p + 1) ? f[2 * p + 1] * 2.f : 0.f;
        o[p] = f2bf(a) | (f2bf(b) << 16);
    }
    ((uint4*)y)[t] = make_uint4(o[0], o[1], o[2], o[3]);
}

// W1 (128x128 f32, [k][n]) -> W1T bf16 [n][k]; W2 (128x64) -> W2T bf16 [n][k]
__global__ void prep_w(const float* __restrict__ W1, const float* __restrict__ W2,
                       ushort* __restrict__ W1T, ushort* __restrict__ W2T) {
    int t = blockIdx.x * blockDim.x + threadIdx.x;
    if (t < 128 * 128) {
        int n = t >> 7, k = t & 127;
        W1T[n * 128 + k] = (ushort)f2bf(W1[k * 128 + n]);
    } else {
        int u = t - 128 * 128;
        if (u < 64 * 128) {
            int n = u >> 7, k = u & 127;
            W2T[n * 128 + k] = (ushort)f2bf(W2[k * 64 + n]);
        }
    }
}

// ---------------- CSR build ----------------

__global__ void hist_kernel(const int* __restrict__ rows, int* __restrict__ deg) {
    int e = blockIdx.x * blockDim.x + threadIdx.x;
    if (e < N_EDGES) {
        int r = rows[e];
        if (r >= 0 && r < N_NODES) atomicAdd(&deg[r], 1);
    }
}

__global__ __launch_bounds__(CSR_BLK) void degsum_kernel(const int* __restrict__ deg,
                                                         int* __restrict__ blockSums) {
    __shared__ int red[CSR_BLK];
    int idx = blockIdx.x * CSR_BLK + threadIdx.x;
    red[threadIdx.x] = (idx < N_NODES) ? deg[idx] : 0;
    __syncthreads();
    for (int off = CSR_BLK / 2; off > 0; off >>= 1) {
        if (threadIdx.x < off) red[threadIdx.x] += red[threadIdx.x + off];
        __syncthreads();
    }
    if (threadIdx.x == 0) blockSums[blockIdx.x] = red[0];
}

__global__ __launch_bounds__(256) void scanblk_kernel(const int* __restrict__ blockSums,
                                                      int* __restrict__ blockOff) {
    __shared__ int s[256];
    int tid = threadIdx.x;
    s[tid] = (tid < CSR_NBLK) ? blockSums[tid] : 0;
    __syncthreads();
    for (int off = 1; off < 256; off <<= 1) {
        int t = (tid >= off) ? s[tid - off] : 0;
        __syncthreads();
        if (tid >= off) s[tid] += t;
        __syncthreads();
    }
    if (tid < CSR_NBLK) blockOff[tid] = (tid == 0) ? 0 : s[tid - 1];
}

__global__ __launch_bounds__(CSR_BLK) void scanfinal_kernel(const int* __restrict__ deg,
                                                            const int* __restrict__ blockOff,
                                                            int* __restrict__ start,
                                                            int* __restrict__ cursor) {
    __shared__ int s[CSR_BLK];
    int tid = threadIdx.x;
    int idx = blockIdx.x * CSR_BLK + tid;
    int d = (idx < N_NODES) ? deg[idx] : 0;
    s[tid] = d;
    __syncthreads();
    for (int off = 1; off < CSR_BLK; off <<= 1) {
        int t = (tid >= off) ? s[tid - off] : 0;
        __syncthreads();
        if (tid >= off) s[tid] += t;
        __syncthreads();
    }
    int incl = s[tid];
    int excl = incl - d;
    int boff = blockOff[blockIdx.x];
    if (idx < N_NODES) {
        start[idx] = boff + excl;
        cursor[idx] = boff + excl;
        if (idx == N_NODES - 1) start[N_NODES] = boff + incl;
    }
}

// packed edge: .x = col, .y = float bits of w
__global__ void scatter_kernel(const int* __restrict__ rows, const int* __restrict__ cols,
                               const float* __restrict__ w, int* __restrict__ cursor,
                               int2* __restrict__ epk) {
    int e = blockIdx.x * blockDim.x + threadIdx.x;
    if (e < N_EDGES) {
        int r = rows[e];
        if (r < 0 || r >= N_NODES) return;            // defensive
        int pos = atomicAdd(&cursor[r], 1);
        if (pos < 0 || pos >= N_EDGES) return;        // defensive: never write OOB
        epk[pos] = make_int2(cols[e], __float_as_int(w[e]));
    }
}

// ---------------- SpMM 128-wide, bf16 gather -> bf16 out ----------------
// 16 lanes/row, uint4 (8 bf16) per lane
__global__ __launch_bounds__(256) void spmm128_bf16(const int* __restrict__ start,
                                                    const int2* __restrict__ epk,
                                                    const ushort* __restrict__ hb,
                                                    ushort* __restrict__ outb) {
    int t = blockIdx.x * blockDim.x + threadIdx.x;
    int r = t >> 4;
    if (r >= N_NODES) return;
    int lane = t & 15;
    int s0 = start[r], s1 = start[r + 1];
    float a0[8] = {0.f, 0.f, 0.f, 0.f, 0.f, 0.f, 0.f, 0.f};
    float a1[8] = {0.f, 0.f, 0.f, 0.f, 0.f, 0.f, 0.f, 0.f};
    int i = s0;
    for (; i + 4 <= s1; i += 4) {
        int2 e0 = epk[i], e1 = epk[i + 1], e2 = epk[i + 2], e3 = epk[i + 3];
        uint4 u0 = *(const uint4*)(hb + (size_t)e0.x * D + lane * 8);
        uint4 u1 = *(const uint4*)(hb + (size_t)e1.x * D + lane * 8);
        uint4 u2 = *(const uint4*)(hb + (size_t)e2.x * D + lane * 8);
        uint4 u3 = *(const uint4*)(hb + (size_t)e3.x * D + lane * 8);
        fma8(a0, u0, __int_as_float(e0.y));
        fma8(a1, u1, __int_as_float(e1.y));
        fma8(a0, u2, __int_as_float(e2.y));
        fma8(a1, u3, __int_as_float(e3.y));
    }
    for (; i < s1; ++i) {
        int2 e = epk[i];
        uint4 u = *(const uint4*)(hb + (size_t)e.x * D + lane * 8);
        fma8(a0, u, __int_as_float(e.y));
    }
    uint4 o;
    o.x = f2bf(a0[0] + a1[0]) | (f2bf(a0[1] + a1[1]) << 16);
    o.y = f2bf(a0[2] + a1[2]) | (f2bf(a0[3] + a1[3]) << 16);
    o.z = f2bf(a0[4] + a1[4]) | (f2bf(a0[5] + a1[5]) << 16);
    o.w = f2bf(a0[6] + a1[6]) | (f2bf(a0[7] + a1[7]) << 16);
    *(uint4*)(outb + (size_t)r * D + lane * 8) = o;
}

// ---------------- SpMM 64-wide + bias, bf16 gather -> fp32 out ----------------
__global__ __launch_bounds__(256) void spmm64_bf16(const int* __restrict__ start,
                                                   const int2* __restrict__ epk,
                                                   const ushort* __restrict__ tb,
                                                   const float* __restrict__ b2,
                                                   float* __restrict__ out) {
    int t = blockIdx.x * blockDim.x + threadIdx.x;
    int r = t >> 3;
    if (r >= N_NODES) return;
    int lane = t & 7;
    int s0 = start[r], s1 = start[r + 1];
    float a0[8] = {0.f, 0.f, 0.f, 0.f, 0.f, 0.f, 0.f, 0.f};
    float a1[8] = {0.f, 0.f, 0.f, 0.f, 0.f, 0.f, 0.f, 0.f};
    int i = s0;
    for (; i + 4 <= s1; i += 4) {
        int2 e0 = epk[i], e1 = epk[i + 1], e2 = epk[i + 2], e3 = epk[i + 3];
        uint4 u0 = *(const uint4*)(tb + (size_t)e0.x * DOUT + lane * 8);
        uint4 u1 = *(const uint4*)(tb + (size_t)e1.x * DOUT + lane * 8);
        uint4 u2 = *(const uint4*)(tb + (size_t)e2.x * DOUT + lane * 8);
        uint4 u3 = *(const uint4*)(tb + (size_t)e3.x * DOUT + lane * 8);
        fma8(a0, u0, __int_as_float(e0.y));
        fma8(a1, u1, __int_as_float(e1.y));
        fma8(a0, u2, __int_as_float(e2.y));
        fma8(a1, u3, __int_as_float(e3.y));
    }
    for (; i < s1; ++i) {
        int2 e = epk[i];
        uint4 u = *(const uint4*)(tb + (size_t)e.x * DOUT + lane * 8);
        fma8(a0, u, __int_as_float(e.y));
    }
    float4 blo = *(const float4*)(b2 + lane * 8);
    float4 bhi = *(const float4*)(b2 + lane * 8 + 4);
    float* op = out + (size_t)r * DOUT + lane * 8;
    *(float4*)(op + 0) = make_float4(a0[0] + a1[0] + blo.x, a0[1] + a1[1] + blo.y,
                                     a0[2] + a1[2] + blo.z, a0[3] + a1[3] + blo.w);
    *(float4*)(op + 4) = make_float4(a0[4] + a1[4] + bhi.x, a0[5] + a1[5] + bhi.y,
                                     a0[6] + a1[6] + bhi.z, a0[7] + a1[7] + bhi.w);
}

// ---------------- fused MFMA lin1+lin2 ----------------
// T = (dropout(relu(Bb @ W1 + b1))) @ W2, all operands bf16, fp32 accum.
// Block = 4 waves x 64 lanes; 64 rows/block (16 rows/wave).
// MFMA 16x16x32 layouts (m89/m91): A row=lane&15, k=8*(lane>>4)+e;
// B col=lane&15, same k; D col=lane&15, row=4*(lane>>4)+v.
#define LROW 136
__global__ __launch_bounds__(256) void lin12_mfma(const ushort* __restrict__ Bb,
                                                  const ushort* __restrict__ W1T,
                                                  const float* __restrict__ b1,
                                                  const ushort* __restrict__ W2T,
                                                  ushort* __restrict__ T,
                                                  uint32_t k0, uint32_t k1) {
    __shared__ ushort h1[4][16][LROW];  // per-wave 16x128 bf16 tile (padded)
    int wave = threadIdx.x >> 6;
    int lane = threadIdx.x & 63;
    int lrow = lane & 15;
    int lhk  = lane >> 4;          // 0..3
    int rowBase = blockIdx.x * 64 + wave * 16;

    // ---- GEMM1: 16x128 rows @ W1 (128x128) ----
    int arow = rowBase + lrow;
    if (arow >= N_NODES) arow = N_NODES - 1;   // clamp (reads only; writes guarded)
    const ushort* aptr = Bb + (size_t)arow * D + lhk * 8;
    bf16x8 afrag[4];
#pragma unroll
    for (int kb = 0; kb < 4; ++kb)
        afrag[kb] = *(const bf16x8*)(aptr + kb * 32);

    f32x4 acc[8];
#pragma unroll
    for (int nt = 0; nt < 8; ++nt) acc[nt] = (f32x4){0.f, 0.f, 0.f, 0.f};
#pragma unroll
    for (int nt = 0; nt < 8; ++nt) {
        const ushort* wp = W1T + (size_t)(nt * 16 + lrow) * 128 + lhk * 8;
#pragma unroll
        for (int kb = 0; kb < 4; ++kb) {
            bf16x8 bfrag = *(const bf16x8*)(wp + kb * 32);
            acc[nt] = __builtin_amdgcn_mfma_f32_16x16x32_bf16(afrag[kb], bfrag, acc[nt], 0, 0, 0);
        }
    }

    // ---- epilogue1: bias, relu, dropout, bf16 -> LDS ----
#pragma unroll
    for (int nt = 0; nt < 8; ++nt) {
        int c = nt * 16 + lrow;
        float bias = b1[c];
#pragma unroll
        for (int v = 0; v < 4; ++v) {
            int rl = lhk * 4 + v;
            int row = rowBase + rl;
            float x = fmaxf(acc[nt][v] + bias, 0.f);
            uint32_t j = (uint32_t)row * 128u + (uint32_t)c;
            x = keep_mask(k0, k1, j) ? x * 2.f : 0.f;
            h1[wave][rl][c] = (ushort)f2bf(x);
        }
    }
    __syncthreads();

    // ---- GEMM2: 16x128 @ W2 (128x64) ----
    bf16x8 a2[4];
#pragma unroll
    for (int kb = 0; kb < 4; ++kb)
        a2[kb] = *(const bf16x8*)&h1[wave][lrow][lhk * 8 + kb * 32];

    f32x4 acc2[4];
#pragma unroll
    for (int nt = 0; nt < 4; ++nt) acc2[nt] = (f32x4){0.f, 0.f, 0.f, 0.f};
#pragma unroll
    for (int nt = 0; nt < 4; ++nt) {
        const ushort* wp = W2T + (size_t)(nt * 16 + lrow) * 128 + lhk * 8;
#pragma unroll
        for (int kb = 0; kb < 4; ++kb) {
            bf16x8 bfrag = *(const bf16x8*)(wp + kb * 32);
            acc2[nt] = __builtin_amdgcn_mfma_f32_16x16x32_bf16(a2[kb], bfrag, acc2[nt], 0, 0, 0);
        }
    }

    // ---- write T (bf16) ----
#pragma unroll
    for (int nt = 0; nt < 4; ++nt) {
        int c = nt * 16 + lrow;
#pragma unroll
        for (int v = 0; v < 4; ++v) {
            int row = rowBase + lhk * 4 + v;
            if (row < N_NODES)
                T[(size_t)row * DOUT + c] = (ushort)f2bf(acc2[nt][v]);
        }
    }
}

extern "C" void kernel_launch(void* const* d_in, const int* in_sizes, int n_in,
                              void* d_out, int out_size, void* d_ws, size_t ws_size,
                              hipStream_t stream) {
    const int*   rows = (const int*)d_in[0];
    const int*   cols = (const int*)d_in[1];
    const float* w    = (const float*)d_in[2];
    const float* X    = (const float*)d_in[3];
    const float* W1   = (const float*)d_in[4];
    const float* b1   = (const float*)d_in[5];
    const float* W2   = (const float*)d_in[6];
    const float* b2   = (const float*)d_in[7];
    float* out = (float*)d_out;

    // Host-side key derivation: split(key(42)) under threefry-partitionable
    uint32_t ka0, ka1, kb0, kb1;
    threefry2x32(0u, 42u, 0u, 0u, ka0, ka1);  // k1 (drop1)
    threefry2x32(0u, 42u, 0u, 1u, kb0, kb1);  // k2 (drop2)

    // workspace layout (16B-aligned blocks, no aliasing)
    char* p = (char*)d_ws;
    ushort* Bb        = (ushort*)p;            p += (size_t)N_NODES * D * 2;      // 12.8 MB (spmm1 out, bf16)
    ushort* Xb        = (ushort*)p;            p += (size_t)N_NODES * D * 2;      // 12.8 MB (drop1 out, bf16)
    ushort* T         = (ushort*)p;            p += (size_t)N_NODES * DOUT * 2;   // 6.4 MB
    int2*   epk       = (int2*)p;              p += (size_t)N_EDGES * 8;          // 6.4 MB
    ushort* W1T       = (ushort*)p;            p += (size_t)128 * 128 * 2;
    ushort* W2T       = (ushort*)p;            p += (size_t)64 * 128 * 2;
    int*    start     = (int*)p;               p += (size_t)(N_NODES + 1) * 4;
    int*    cursor    = (int*)p;               p += (size_t)N_NODES * 4;
    int*    deg       = (int*)p;               p += (size_t)N_NODES * 4;
    int*    blockSums = (int*)p;               p += (size_t)CSR_NBLK * 4;
    int*    blockOff  = (int*)p;               p += (size_t)CSR_NBLK * 4;

    // ---- CSR build + weight prep ----
    hipMemsetAsync(deg, 0, (size_t)N_NODES * 4, stream);
    hist_kernel<<<(N_EDGES + 255) / 256, 256, 0, stream>>>(rows, deg);
    degsum_kernel<<<CSR_NBLK, CSR_BLK, 0, stream>>>(deg, blockSums);
    scanblk_kernel<<<1, 256, 0, stream>>>(blockSums, blockOff);
    scanfinal_kernel<<<CSR_NBLK, CSR_BLK, 0, stream>>>(deg, blockOff, start, cursor);
    scatter_kernel<<<(N_EDGES + 255) / 256, 256, 0, stream>>>(rows, cols, w, cursor, epk);
    prep_w<<<(128 * 128 + 64 * 128 + 255) / 256, 256, 0, stream>>>(W1, W2, W1T, W2T);

    // ---- forward ----
    int n8 = N_NODES * D / 8;  // 800000
    drop8_kernel<<<(n8 + 255) / 256, 256, 0, stream>>>(X, Xb, ka0, ka1, n8);
    spmm128_bf16<<<((size_t)N_NODES * 16 + 255) / 256, 256, 0, stream>>>(start, epk, Xb, Bb);
    lin12_mfma<<<(N_NODES + 63) / 64, 256, 0, stream>>>(Bb, W1T, b1, W2T, T, kb0, kb1);
    spmm64_bf16<<<((size_t)N_NODES * 8 + 255) / 256, 256, 0, stream>>>(start, epk, T, b2, out);
}

// Round 11
// 183.394 us; speedup vs baseline: 16.1658x; 1.0954x over previous
//
#include <hip/hip_runtime.h>
#include <stdint.h>

#define N_NODES 50000
#define N_EDGES 800000
#define D 128
#define DOUT 64

#define CSR_BLK 256
#define CSR_NBLK ((N_NODES + CSR_BLK - 1) / CSR_BLK)  // 196

#define BSH 7                                  // rows per bucket = 128
#define NBUCK ((N_NODES + 127) >> BSH)         // 391
#define EPB 4096                               // edges per bucket_scatter block
#define SC_NBLK ((N_EDGES + EPB - 1) / EPB)    // 196

typedef short bf16x8 __attribute__((ext_vector_type(8)));
typedef float f32x4 __attribute__((ext_vector_type(4)));

__host__ __device__ inline uint32_t rotl32(uint32_t v, int d) {
    return (v << d) | (v >> (32 - d));
}

// JAX threefry2x32 (20 rounds), matches jax/_src/prng.py
__host__ __device__ inline void threefry2x32(uint32_t k0, uint32_t k1,
                                             uint32_t x0, uint32_t x1,
                                             uint32_t& o0, uint32_t& o1) {
    uint32_t ks2 = 0x1BD11BDAu ^ k0 ^ k1;
    x0 += k0; x1 += k1;
#define TFR(d) { x0 += x1; x1 = rotl32(x1, d); x1 ^= x0; }
    TFR(13) TFR(15) TFR(26) TFR(6)
    x0 += k1;  x1 += ks2 + 1u;
    TFR(17) TFR(29) TFR(16) TFR(24)
    x0 += ks2; x1 += k0 + 2u;
    TFR(13) TFR(15) TFR(26) TFR(6)
    x0 += k0;  x1 += k1 + 3u;
    TFR(17) TFR(29) TFR(16) TFR(24)
    x0 += k1;  x1 += ks2 + 4u;
    TFR(13) TFR(15) TFR(26) TFR(6)
    x0 += ks2; x1 += k0 + 5u;
#undef TFR
    o0 = x0; o1 = x1;
}

// partitionable random_bits(32) for flat index j: bits = x0^x1 of threefry(key,(0,j))
__device__ inline bool keep_mask(uint32_t k0, uint32_t k1, uint32_t j) {
    uint32_t b0, b1;
    threefry2x32(k0, k1, 0u, j, b0, b1);
    uint32_t bits = b0 ^ b1;
    float u = __uint_as_float((bits >> 9) | 0x3f800000u) - 1.0f;
    return u < 0.5f;
}

// fp32 -> bf16 (round-to-nearest-even), and unpack helpers
__device__ inline uint32_t f2bf(float f) {
    uint32_t u = __float_as_uint(f);
    return (u + 0x7fffu + ((u >> 16) & 1u)) >> 16;
}
__device__ inline float bf2f_lo(uint32_t u) { return __uint_as_float(u << 16); }
__device__ inline float bf2f_hi(uint32_t u) { return __uint_as_float(u & 0xffff0000u); }

__device__ inline void fma8(float* a, uint4 u, float w) {
    a[0] = fmaf(w, bf2f_lo(u.x), a[0]);
    a[1] = fmaf(w, bf2f_hi(u.x), a[1]);
    a[2] = fmaf(w, bf2f_lo(u.y), a[2]);
    a[3] = fmaf(w, bf2f_hi(u.y), a[3]);
    a[4] = fmaf(w, bf2f_lo(u.z), a[4]);
    a[5] = fmaf(w, bf2f_hi(u.z), a[5]);
    a[6] = fmaf(w, bf2f_lo(u.w), a[6]);
    a[7] = fmaf(w, bf2f_hi(u.w), a[7]);
}

// dropout(X) -> bf16, 8 elems/thread
__global__ void drop8_kernel(const float* __restrict__ x, ushort* __restrict__ y,
                             uint32_t k0, uint32_t k1, int n8) {
    int t = blockIdx.x * blockDim.x + threadIdx.x;
    if (t >= n8) return;
    float4 v0 = ((const float4*)x)[t * 2];
    float4 v1 = ((const float4*)x)[t * 2 + 1];
    uint32_t j = (uint32_t)t * 8u;
    float f[8] = {v0.x, v0.y, v0.z, v0.w, v1.x, v1.y, v1.z, v1.w};
    uint32_t o[4];
#pragma unroll
    for (int p = 0; p < 4; ++p) {
        float a = keep_mask(k0, k1, j + 2 * p)     ? f[2 * p] * 2.f     : 0.f;
        float b = keep_mask(k0, k1, j + 2 * p + 1) ? f[2 * p + 1] * 2.f : 0.f;
        o[p] = f2bf(a) | (f2bf(b) << 16);
    }
    ((uint4*)y)[t] = make_uint4(o[0], o[1], o[2], o[3]);
}

// W1 (128x128 f32, [k][n]) -> W1T bf16 [n][k]; W2 (128x64) -> W2T bf16 [n][k]
__global__ void prep_w(const float* __restrict__ W1, const float* __restrict__ W2,
                       ushort* __restrict__ W1T, ushort* __restrict__ W2T) {
    int t = blockIdx.x * blockDim.x + threadIdx.x;
    if (t < 128 * 128) {
        int n = t >> 7, k = t & 127;
        W1T[n * 128 + k] = (ushort)f2bf(W1[k * 128 + n]);
    } else {
        int u = t - 128 * 128;
        if (u < 64 * 128) {
            int n = u >> 7, k = u & 127;
            W2T[n * 128 + k] = (ushort)f2bf(W2[k * 64 + n]);
        }
    }
}

// ---------------- CSR build ----------------

__global__ void hist_kernel(const int* __restrict__ rows, int* __restrict__ deg) {
    int e = blockIdx.x * blockDim.x + threadIdx.x;
    if (e < N_EDGES) {
        int r = rows[e];
        if (r >= 0 && r < N_NODES) atomicAdd(&deg[r], 1);
    }
}

__global__ __launch_bounds__(CSR_BLK) void degsum_kernel(const int* __restrict__ deg,
                                                         int* __restrict__ blockSums) {
    __shared__ int red[CSR_BLK];
    int idx = blockIdx.x * CSR_BLK + threadIdx.x;
    red[threadIdx.x] = (idx < N_NODES) ? deg[idx] : 0;
    __syncthreads();
    for (int off = CSR_BLK / 2; off > 0; off >>= 1) {
        if (threadIdx.x < off) red[threadIdx.x] += red[threadIdx.x + off];
        __syncthreads();
    }
    if (threadIdx.x == 0) blockSums[blockIdx.x] = red[0];
}

__global__ __launch_bounds__(256) void scanblk_kernel(const int* __restrict__ blockSums,
                                                      int* __restrict__ blockOff) {
    __shared__ int s[256];
    int tid = threadIdx.x;
    s[tid] = (tid < CSR_NBLK) ? blockSums[tid] : 0;
    __syncthreads();
    for (int off = 1; off < 256; off <<= 1) {
        int t = (tid >= off) ? s[tid - off] : 0;
        __syncthreads();
        if (tid >= off) s[tid] += t;
        __syncthreads();
    }
    if (tid < CSR_NBLK) blockOff[tid] = (tid == 0) ? 0 : s[tid - 1];
}

__global__ __launch_bounds__(CSR_BLK) void scanfinal_kernel(const int* __restrict__ deg,
                                                            const int* __restrict__ blockOff,
                                                            int* __restrict__ start) {
    __shared__ int s[CSR_BLK];
    int tid = threadIdx.x;
    int idx = blockIdx.x * CSR_BLK + tid;
    int d = (idx < N_NODES) ? deg[idx] : 0;
    s[tid] = d;
    __syncthreads();
    for (int off = 1; off < CSR_BLK; off <<= 1) {
        int t = (tid >= off) ? s[tid - off] : 0;
        __syncthreads();
        if (tid >= off) s[tid] += t;
        __syncthreads();
    }
    int incl = s[tid];
    int excl = incl - d;
    int boff = blockOff[blockIdx.x];
    if (idx < N_NODES) {
        start[idx] = boff + excl;
        if (idx == N_NODES - 1) start[N_NODES] = boff + incl;
    }
}

// bcur[b] = start[min(b<<BSH, N_NODES)]
__global__ void initb_kernel(const int* __restrict__ start, int* __restrict__ bcur) {
    int b = blockIdx.x * blockDim.x + threadIdx.x;
    if (b < NBUCK) {
        int r = b << BSH;
        if (r > N_NODES) r = N_NODES;
        bcur[b] = start[r];
    }
}

// Phase 1: bucket edges by row>>BSH into tmp arrays (bucket-contiguous regions)
__global__ __launch_bounds__(256) void bucket_scatter(const int* __restrict__ rows,
                                                      const int* __restrict__ cols,
                                                      const float* __restrict__ w,
                                                      int* __restrict__ bcur,
                                                      int* __restrict__ tmpRow,
                                                      int2* __restrict__ tmpCW) {
    __shared__ int hist[NBUCK];
    __shared__ int base[NBUCK];
    int e0 = blockIdx.x * EPB;
    for (int i = threadIdx.x; i < NBUCK; i += 256) hist[i] = 0;
    __syncthreads();
    int myrow[16];
#pragma unroll
    for (int k = 0; k < 16; ++k) {
        int e = e0 + k * 256 + threadIdx.x;
        int r = (e < N_EDGES) ? rows[e] : -1;
        if (r < 0 || r >= N_NODES) r = -1;   // defensive
        myrow[k] = r;
        if (r >= 0) atomicAdd(&hist[r >> BSH], 1);
    }
    __syncthreads();
    for (int b = threadIdx.x; b < NBUCK; b += 256) {
        int c = hist[b];
        base[b] = (c > 0) ? atomicAdd(&bcur[b], c) : 0;
        hist[b] = 0;   // reuse as running offset
    }
    __syncthreads();
#pragma unroll
    for (int k = 0; k < 16; ++k) {
        int r = myrow[k];
        if (r < 0) continue;
        int e = e0 + k * 256 + threadIdx.x;
        int b = r >> BSH;
        int pos = base[b] + atomicAdd(&hist[b], 1);
        if (pos < 0 || pos >= N_EDGES) continue;   // defensive
        tmpRow[pos] = r;
        tmpCW[pos] = make_int2(cols[e], __float_as_int(w[e]));
    }
}

// Phase 2: one block per bucket; exact CSR slot via LDS cursors; localized writes
__global__ __launch_bounds__(256) void scatter2(const int* __restrict__ start,
                                                const int* __restrict__ tmpRow,
                                                const int2* __restrict__ tmpCW,
                                                int2* __restrict__ epk) {
    __shared__ int lcur[1 << BSH];
    int b = blockIdx.x;
    int r0 = b << BSH;
    int r1 = r0 + (1 << BSH);
    if (r1 > N_NODES) r1 = N_NODES;
    int nr = r1 - r0;
    for (int i = threadIdx.x; i < nr; i += 256) lcur[i] = start[r0 + i];
    __syncthreads();
    int e0 = start[r0], e1 = start[r1];
    for (int i = e0 + threadIdx.x; i < e1; i += 256) {
        int r = tmpRow[i];
        if (r < r0 || r >= r1) continue;           // defensive
        int pos = atomicAdd(&lcur[r - r0], 1);
        if (pos < 0 || pos >= N_EDGES) continue;   // defensive
        epk[pos] = tmpCW[i];
    }
}

// ---------------- SpMM 128-wide, bf16 gather -> bf16 out ----------------
// 16 lanes/row, uint4 (8 bf16) per lane
__global__ __launch_bounds__(256) void spmm128_bf16(const int* __restrict__ start,
                                                    const int2* __restrict__ epk,
                                                    const ushort* __restrict__ hb,
                                                    ushort* __restrict__ outb) {
    int t = blockIdx.x * blockDim.x + threadIdx.x;
    int r = t >> 4;
    if (r >= N_NODES) return;
    int lane = t & 15;
    int s0 = start[r], s1 = start[r + 1];
    float a0[8] = {0.f, 0.f, 0.f, 0.f, 0.f, 0.f, 0.f, 0.f};
    float a1[8] = {0.f, 0.f, 0.f, 0.f, 0.f, 0.f, 0.f, 0.f};
    int i = s0;
    for (; i + 4 <= s1; i += 4) {
        int2 e0 = epk[i], e1 = epk[i + 1], e2 = epk[i + 2], e3 = epk[i + 3];
        uint4 u0 = *(const uint4*)(hb + (size_t)e0.x * D + lane * 8);
        uint4 u1 = *(const uint4*)(hb + (size_t)e1.x * D + lane * 8);
        uint4 u2 = *(const uint4*)(hb + (size_t)e2.x * D + lane * 8);
        uint4 u3 = *(const uint4*)(hb + (size_t)e3.x * D + lane * 8);
        fma8(a0, u0, __int_as_float(e0.y));
        fma8(a1, u1, __int_as_float(e1.y));
        fma8(a0, u2, __int_as_float(e2.y));
        fma8(a1, u3, __int_as_float(e3.y));
    }
    for (; i < s1; ++i) {
        int2 e = epk[i];
        uint4 u = *(const uint4*)(hb + (size_t)e.x * D + lane * 8);
        fma8(a0, u, __int_as_float(e.y));
    }
    uint4 o;
    o.x = f2bf(a0[0] + a1[0]) | (f2bf(a0[1] + a1[1]) << 16);
    o.y = f2bf(a0[2] + a1[2]) | (f2bf(a0[3] + a1[3]) << 16);
    o.z = f2bf(a0[4] + a1[4]) | (f2bf(a0[5] + a1[5]) << 16);
    o.w = f2bf(a0[6] + a1[6]) | (f2bf(a0[7] + a1[7]) << 16);
    *(uint4*)(outb + (size_t)r * D + lane * 8) = o;
}

// ---------------- SpMM 64-wide + bias, bf16 gather -> fp32 out ----------------
__global__ __launch_bounds__(256) void spmm64_bf16(const int* __restrict__ start,
                                                   const int2* __restrict__ epk,
                                                   const ushort* __restrict__ tb,
                                                   const float* __restrict__ b2,
                                                   float* __restrict__ out) {
    int t = blockIdx.x * blockDim.x + threadIdx.x;
    int r = t >> 3;
    if (r >= N_NODES) return;
    int lane = t & 7;
    int s0 = start[r], s1 = start[r + 1];
    float a0[8] = {0.f, 0.f, 0.f, 0.f, 0.f, 0.f, 0.f, 0.f};
    float a1[8] = {0.f, 0.f, 0.f, 0.f, 0.f, 0.f, 0.f, 0.f};
    int i = s0;
    for (; i + 4 <= s1; i += 4) {
        int2 e0 = epk[i], e1 = epk[i + 1], e2 = epk[i + 2], e3 = epk[i + 3];
        uint4 u0 = *(const uint4*)(tb + (size_t)e0.x * DOUT + lane * 8);
        uint4 u1 = *(const uint4*)(tb + (size_t)e1.x * DOUT + lane * 8);
        uint4 u2 = *(const uint4*)(tb + (size_t)e2.x * DOUT + lane * 8);
        uint4 u3 = *(const uint4*)(tb + (size_t)e3.x * DOUT + lane * 8);
        fma8(a0, u0, __int_as_float(e0.y));
        fma8(a1, u1, __int_as_float(e1.y));
        fma8(a0, u2, __int_as_float(e2.y));
        fma8(a1, u3, __int_as_float(e3.y));
    }
    for (; i < s1; ++i) {
        int2 e = epk[i];
        uint4 u = *(const uint4*)(tb + (size_t)e.x * DOUT + lane * 8);
        fma8(a0, u, __int_as_float(e.y));
    }
    float4 blo = *(const float4*)(b2 + lane * 8);
    float4 bhi = *(const float4*)(b2 + lane * 8 + 4);
    float* op = out + (size_t)r * DOUT + lane * 8;
    *(float4*)(op + 0) = make_float4(a0[0] + a1[0] + blo.x, a0[1] + a1[1] + blo.y,
                                     a0[2] + a1[2] + blo.z, a0[3] + a1[3] + blo.w);
    *(float4*)(op + 4) = make_float4(a0[4] + a1[4] + bhi.x, a0[5] + a1[5] + bhi.y,
                                     a0[6] + a1[6] + bhi.z, a0[7] + a1[7] + bhi.w);
}

// ---------------- fused MFMA lin1+lin2 ----------------
// T = (dropout(relu(Bb @ W1 + b1))) @ W2, all operands bf16, fp32 accum.
#define LROW 136
__global__ __launch_bounds__(256) void lin12_mfma(const ushort* __restrict__ Bb,
                                                  const ushort* __restrict__ W1T,
                                                  const float* __restrict__ b1,
                                                  const ushort* __restrict__ W2T,
                                                  ushort* __restrict__ T,
                                                  uint32_t k0, uint32_t k1) {
    __shared__ ushort h1[4][16][LROW];  // per-wave 16x128 bf16 tile (padded)
    int wave = threadIdx.x >> 6;
    int lane = threadIdx.x & 63;
    int lrow = lane & 15;
    int lhk  = lane >> 4;          // 0..3
    int rowBase = blockIdx.x * 64 + wave * 16;

    // ---- GEMM1: 16x128 rows @ W1 (128x128) ----
    int arow = rowBase + lrow;
    if (arow >= N_NODES) arow = N_NODES - 1;   // clamp (reads only; writes guarded)
    const ushort* aptr = Bb + (size_t)arow * D + lhk * 8;
    bf16x8 afrag[4];
#pragma unroll
    for (int kb = 0; kb < 4; ++kb)
        afrag[kb] = *(const bf16x8*)(aptr + kb * 32);

    f32x4 acc[8];
#pragma unroll
    for (int nt = 0; nt < 8; ++nt) acc[nt] = (f32x4){0.f, 0.f, 0.f, 0.f};
#pragma unroll
    for (int nt = 0; nt < 8; ++nt) {
        const ushort* wp = W1T + (size_t)(nt * 16 + lrow) * 128 + lhk * 8;
#pragma unroll
        for (int kb = 0; kb < 4; ++kb) {
            bf16x8 bfrag = *(const bf16x8*)(wp + kb * 32);
            acc[nt] = __builtin_amdgcn_mfma_f32_16x16x32_bf16(afrag[kb], bfrag, acc[nt], 0, 0, 0);
        }
    }

    // ---- epilogue1: bias, relu, dropout, bf16 -> LDS ----
#pragma unroll
    for (int nt = 0; nt < 8; ++nt) {
        int c = nt * 16 + lrow;
        float bias = b1[c];
#pragma unroll
        for (int v = 0; v < 4; ++v) {
            int rl = lhk * 4 + v;
            int row = rowBase + rl;
            float x = fmaxf(acc[nt][v] + bias, 0.f);
            uint32_t j = (uint32_t)row * 128u + (uint32_t)c;
            x = keep_mask(k0, k1, j) ? x * 2.f : 0.f;
            h1[wave][rl][c] = (ushort)f2bf(x);
        }
    }
    __syncthreads();

    // ---- GEMM2: 16x128 @ W2 (128x64) ----
    bf16x8 a2[4];
#pragma unroll
    for (int kb = 0; kb < 4; ++kb)
        a2[kb] = *(const bf16x8*)&h1[wave][lrow][lhk * 8 + kb * 32];

    f32x4 acc2[4];
#pragma unroll
    for (int nt = 0; nt < 4; ++nt) acc2[nt] = (f32x4){0.f, 0.f, 0.f, 0.f};
#pragma unroll
    for (int nt = 0; nt < 4; ++nt) {
        const ushort* wp = W2T + (size_t)(nt * 16 + lrow) * 128 + lhk * 8;
#pragma unroll
        for (int kb = 0; kb < 4; ++kb) {
            bf16x8 bfrag = *(const bf16x8*)(wp + kb * 32);
            acc2[nt] = __builtin_amdgcn_mfma_f32_16x16x32_bf16(a2[kb], bfrag, acc2[nt], 0, 0, 0);
        }
    }

    // ---- write T (bf16) ----
#pragma unroll
    for (int nt = 0; nt < 4; ++nt) {
        int c = nt * 16 + lrow;
#pragma unroll
        for (int v = 0; v < 4; ++v) {
            int row = rowBase + lhk * 4 + v;
            if (row < N_NODES)
                T[(size_t)row * DOUT + c] = (ushort)f2bf(acc2[nt][v]);
        }
    }
}

extern "C" void kernel_launch(void* const* d_in, const int* in_sizes, int n_in,
                              void* d_out, int out_size, void* d_ws, size_t ws_size,
                              hipStream_t stream) {
    const int*   rows = (const int*)d_in[0];
    const int*   cols = (const int*)d_in[1];
    const float* w    = (const float*)d_in[2];
    const float* X    = (const float*)d_in[3];
    const float* W1   = (const float*)d_in[4];
    const float* b1   = (const float*)d_in[5];
    const float* W2   = (const float*)d_in[6];
    const float* b2   = (const float*)d_in[7];
    float* out = (float*)d_out;

    // Host-side key derivation: split(key(42)) under threefry-partitionable
    uint32_t ka0, ka1, kb0, kb1;
    threefry2x32(0u, 42u, 0u, 0u, ka0, ka1);  // k1 (drop1)
    threefry2x32(0u, 42u, 0u, 1u, kb0, kb1);  // k2 (drop2)

    // workspace layout (16B-aligned blocks, no aliasing)
    char* p = (char*)d_ws;
    ushort* Bb        = (ushort*)p;            p += (size_t)N_NODES * D * 2;      // 12.8 MB
    ushort* Xb        = (ushort*)p;            p += (size_t)N_NODES * D * 2;      // 12.8 MB
    ushort* T         = (ushort*)p;            p += (size_t)N_NODES * DOUT * 2;   // 6.4 MB
    int2*   epk       = (int2*)p;              p += (size_t)N_EDGES * 8;          // 6.4 MB
    int2*   tmpCW     = (int2*)p;              p += (size_t)N_EDGES * 8;          // 6.4 MB
    int*    tmpRow    = (int*)p;               p += (size_t)N_EDGES * 4;          // 3.2 MB
    ushort* W1T       = (ushort*)p;            p += (size_t)128 * 128 * 2;
    ushort* W2T       = (ushort*)p;            p += (size_t)64 * 128 * 2;
    int*    start     = (int*)p;               p += (size_t)(N_NODES + 1) * 4;
    int*    deg       = (int*)p;               p += (size_t)N_NODES * 4;
    int*    bcur      = (int*)p;               p += (size_t)NBUCK * 4;
    int*    blockSums = (int*)p;               p += (size_t)CSR_NBLK * 4;
    int*    blockOff  = (int*)p;               p += (size_t)CSR_NBLK * 4;

    // ---- CSR build (two-phase bucket sort) + weight prep ----
    hipMemsetAsync(deg, 0, (size_t)N_NODES * 4, stream);
    hist_kernel<<<(N_EDGES + 255) / 256, 256, 0, stream>>>(rows, deg);
    degsum_kernel<<<CSR_NBLK, CSR_BLK, 0, stream>>>(deg, blockSums);
    scanblk_kernel<<<1, 256, 0, stream>>>(blockSums, blockOff);
    scanfinal_kernel<<<CSR_NBLK, CSR_BLK, 0, stream>>>(deg, blockOff, start);
    initb_kernel<<<(NBUCK + 255) / 256, 256, 0, stream>>>(start, bcur);
    bucket_scatter<<<SC_NBLK, 256, 0, stream>>>(rows, cols, w, bcur, tmpRow, tmpCW);
    scatter2<<<NBUCK, 256, 0, stream>>>(start, tmpRow, tmpCW, epk);
    prep_w<<<(128 * 128 + 64 * 128 + 255) / 256, 256, 0, stream>>>(W1, W2, W1T, W2T);

    // ---- forward ----
    int n8 = N_NODES * D / 8;  // 800000
    drop8_kernel<<<(n8 + 255) / 256, 256, 0, stream>>>(X, Xb, ka0, ka1, n8);
    spmm128_bf16<<<((size_t)N_NODES * 16 + 255) / 256, 256, 0, stream>>>(start, epk, Xb, Bb);
    lin12_mfma<<<(N_NODES + 63) / 64, 256, 0, stream>>>(Bb, W1T, b1, W2T, T, kb0, kb1);
    spmm64_bf16<<<((size_t)N_NODES * 8 + 255) / 256, 256, 0, stream>>>(start, epk, T, b2, out);
}